// Round 1
// baseline (934.041 us; speedup 1.0000x reference)
//
#include <hip/hip_runtime.h>

typedef __attribute__((ext_vector_type(8))) __bf16 bf8;
typedef __attribute__((ext_vector_type(4))) __bf16 bf4;
typedef __attribute__((ext_vector_type(4))) float f32x4;

#define DEVI static __device__ __forceinline__

// async global->LDS, 16B per lane. LDS dest must be linear in lane order.
DEVI void gload_lds16(const void* g, void* l) {
  __builtin_amdgcn_global_load_lds(
      (const __attribute__((address_space(1))) unsigned int*)g,
      (__attribute__((address_space(3))) unsigned int*)l, 16, 0, 0);
}

// ---------------- f32 -> bf16 convert ----------------
__global__ __launch_bounds__(256) void cvt_kernel(const float* __restrict__ in,
                                                  __bf16* __restrict__ out, int n4) {
  int stride = gridDim.x * blockDim.x;
  for (int i = blockIdx.x * blockDim.x + threadIdx.x; i < n4; i += stride) {
    f32x4 v = reinterpret_cast<const f32x4*>(in)[i];
    bf4 o;
    o[0] = (__bf16)v[0]; o[1] = (__bf16)v[1]; o[2] = (__bf16)v[2]; o[3] = (__bf16)v[3];
    reinterpret_cast<bf4*>(out)[i] = o;
  }
}

// ---------------- generic projection GEMM ----------------
// C[m][n] = sum_k A[m][k] * Bw[n][k]  (+bias[n]) ; M=16384, N=1024, K=1024
// MODE 0: out bf16, *= rel[n], heads layout  [b,h,q,c]
// MODE 1: out bf16, transposed heads layout  [b,h,c,q]   (f_v -> f_vT)
// MODE 2: out f32 flat [m*1024+n]
template <int MODE>
__global__ __launch_bounds__(256) void gemm_proj(
    const __bf16* __restrict__ A, const __bf16* __restrict__ Bw,
    const float* __restrict__ bias, const float* __restrict__ rel,
    __bf16* __restrict__ obf, float* __restrict__ of32) {
  __shared__ alignas(16) __bf16 As[128 * 64];
  __shared__ alignas(16) __bf16 Bs[128 * 64];
  const int tid = threadIdx.x;
  const int lane = tid & 63;
  const int wave = tid >> 6;
  const int wr = wave >> 1, wc = wave & 1;
  const int lr = lane & 15, lk = (lane >> 4) * 8;

  f32x4 acc[4][4];
#pragma unroll
  for (int i = 0; i < 4; ++i)
#pragma unroll
    for (int j = 0; j < 4; ++j)
#pragma unroll
      for (int e = 0; e < 4; ++e) acc[i][j][e] = 0.f;

  const __bf16* Ab = A + (size_t)blockIdx.y * 128 * 1024;
  const __bf16* Bb = Bw + (size_t)blockIdx.x * 128 * 1024;
  const int sr = tid >> 3;
  const int sc = (tid & 7) * 8;

  for (int kt = 0; kt < 1024; kt += 64) {
#pragma unroll
    for (int i = 0; i < 4; ++i) {
      gload_lds16(Ab + (size_t)(sr + i * 32) * 1024 + kt + sc, As + tid * 8 + i * 2048);
      gload_lds16(Bb + (size_t)(sr + i * 32) * 1024 + kt + sc, Bs + tid * 8 + i * 2048);
    }
    __syncthreads();
#pragma unroll
    for (int kk = 0; kk < 64; kk += 32) {
      bf8 a[4], b[4];
#pragma unroll
      for (int mi = 0; mi < 4; ++mi)
        a[mi] = *reinterpret_cast<const bf8*>(&As[(wr * 64 + mi * 16 + lr) * 64 + kk + lk]);
#pragma unroll
      for (int ni = 0; ni < 4; ++ni)
        b[ni] = *reinterpret_cast<const bf8*>(&Bs[(wc * 64 + ni * 16 + lr) * 64 + kk + lk]);
#pragma unroll
      for (int mi = 0; mi < 4; ++mi)
#pragma unroll
        for (int ni = 0; ni < 4; ++ni)
          acc[mi][ni] = __builtin_amdgcn_mfma_f32_16x16x32_bf16(a[mi], b[ni], acc[mi][ni], 0, 0, 0);
    }
    __syncthreads();
  }

  const int mBase = blockIdx.y * 128 + wr * 64;
  const int nBase = blockIdx.x * 128 + wc * 64;
#pragma unroll
  for (int mi = 0; mi < 4; ++mi) {
#pragma unroll
    for (int ni = 0; ni < 4; ++ni) {
      const int n = nBase + ni * 16 + lr;
#pragma unroll
      for (int r = 0; r < 4; ++r) {
        const int m = mBase + mi * 16 + (lane >> 4) * 4 + r;
        float v = acc[mi][ni][r] + bias[n];
        if (MODE == 0) v *= rel[n];
        if (MODE == 2) {
          of32[(size_t)m * 1024 + n] = v;
        } else if (MODE == 0) {
          size_t idx = ((size_t)((m >> 9) * 8 + (n >> 7))) * 65536 +
                       (size_t)(m & 511) * 128 + (n & 127);
          obf[idx] = (__bf16)v;
        } else {
          size_t idx = ((size_t)((m >> 9) * 8 + (n >> 7))) * 65536 +
                       (size_t)(n & 127) * 512 + (m & 511);
          obf[idx] = (__bf16)v;
        }
      }
    }
  }
}

// ---------------- adj: per-head column softmax, scaled by 1e4 ----------------
// adjs[h][i][j] = 10000 * softmax_j( (j==i) ? 0 : dot18(col_head[h,i], col_tail[h,j]) )
__global__ __launch_bounds__(256) void adj_kernel(const float* __restrict__ ch_all,
                                                  const float* __restrict__ ct_all,
                                                  float* __restrict__ adjs) {
  const int wave = threadIdx.x >> 6, lane = threadIdx.x & 63;
  const int row = blockIdx.x * 4 + wave;  // 0..4095
  const int h = row >> 9, i = row & 511;
  float ch[18];
  const float* chp = ch_all + ((size_t)h * 512 + i) * 18;
#pragma unroll
  for (int t = 0; t < 18; ++t) ch[t] = chp[t];
  float e[8];
  float m = -1e30f;
#pragma unroll
  for (int jj = 0; jj < 8; ++jj) {
    const int j = jj * 64 + lane;
    const float* ctp = ct_all + ((size_t)h * 512 + j) * 18;
    float d = 0.f;
#pragma unroll
    for (int t = 0; t < 18; ++t) d += ch[t] * ctp[t];
    if (j == i) d = 0.f;
    e[jj] = d;
    m = fmaxf(m, d);
  }
#pragma unroll
  for (int off = 32; off >= 1; off >>= 1) m = fmaxf(m, __shfl_xor(m, off));
  float s = 0.f;
#pragma unroll
  for (int jj = 0; jj < 8; ++jj) { e[jj] = __expf(e[jj] - m); s += e[jj]; }
#pragma unroll
  for (int off = 32; off >= 1; off >>= 1) s += __shfl_xor(s, off);
  const float inv = 10000.f / s;
  float* op = adjs + (size_t)h * 262144 + (size_t)i * 512;
#pragma unroll
  for (int jj = 0; jj < 8; ++jj) op[jj * 64 + lane] = e[jj] * inv;
}

// ---------------- scores: S = f_head . f_tail^T / sqrt(128) + adjs ----------------
__global__ __launch_bounds__(256) void scores_kernel(
    const __bf16* __restrict__ fh, const __bf16* __restrict__ ft,
    const float* __restrict__ adjs, float* __restrict__ fr) {
  __shared__ alignas(16) __bf16 Ah[128 * 128];
  __shared__ alignas(16) __bf16 At[128 * 128];
  const int tid = threadIdx.x;
  const int bh = blockIdx.z;
  const int h = bh & 7;
  const int qt = blockIdx.y, kt = blockIdx.x;
  const __bf16* ga = fh + (size_t)bh * 65536 + (size_t)qt * 16384;
  const __bf16* gb = ft + (size_t)bh * 65536 + (size_t)kt * 16384;
#pragma unroll
  for (int i = 0; i < 8; ++i) {
    gload_lds16(ga + (i * 256 + tid) * 8, Ah + (i * 256 + tid) * 8);
    gload_lds16(gb + (i * 256 + tid) * 8, At + (i * 256 + tid) * 8);
  }
  __syncthreads();
  const int lane = tid & 63, wave = tid >> 6;
  const int wr = wave >> 1, wc = wave & 1;
  const int lr = lane & 15, lk = (lane >> 4) * 8;
  f32x4 acc[4][4];
#pragma unroll
  for (int i = 0; i < 4; ++i)
#pragma unroll
    for (int j = 0; j < 4; ++j)
#pragma unroll
      for (int e = 0; e < 4; ++e) acc[i][j][e] = 0.f;
#pragma unroll
  for (int kk = 0; kk < 128; kk += 32) {
    bf8 a[4], b[4];
#pragma unroll
    for (int mi = 0; mi < 4; ++mi)
      a[mi] = *reinterpret_cast<const bf8*>(&Ah[(wr * 64 + mi * 16 + lr) * 128 + kk + lk]);
#pragma unroll
    for (int ni = 0; ni < 4; ++ni)
      b[ni] = *reinterpret_cast<const bf8*>(&At[(wc * 64 + ni * 16 + lr) * 128 + kk + lk]);
#pragma unroll
    for (int mi = 0; mi < 4; ++mi)
#pragma unroll
      for (int ni = 0; ni < 4; ++ni)
        acc[mi][ni] = __builtin_amdgcn_mfma_f32_16x16x32_bf16(a[mi], b[ni], acc[mi][ni], 0, 0, 0);
  }
  const float scale = 0.08838834764831845f;  // 1/sqrt(128)
#pragma unroll
  for (int mi = 0; mi < 4; ++mi) {
#pragma unroll
    for (int ni = 0; ni < 4; ++ni) {
      const int kg = kt * 128 + wc * 64 + ni * 16 + lr;
#pragma unroll
      for (int r = 0; r < 4; ++r) {
        const int qg = qt * 128 + wr * 64 + mi * 16 + (lane >> 4) * 4 + r;
        fr[(size_t)bh * 262144 + (size_t)qg * 512 + kg] =
            acc[mi][ni][r] * scale + adjs[(size_t)h * 262144 + (size_t)qg * 512 + kg];
      }
    }
  }
}

// ---------------- row softmax over fr (in place) ----------------
__global__ __launch_bounds__(256) void softmax_kernel(float* __restrict__ fr) {
  const int wave = threadIdx.x >> 6, lane = threadIdx.x & 63;
  const size_t row = (size_t)blockIdx.x * 4 + wave;
  float* p = fr + row * 512 + lane * 8;
  f32x4 v0 = *reinterpret_cast<f32x4*>(p);
  f32x4 v1 = *reinterpret_cast<f32x4*>(p + 4);
  float m = v0[0];
#pragma unroll
  for (int e = 1; e < 4; ++e) m = fmaxf(m, v0[e]);
#pragma unroll
  for (int e = 0; e < 4; ++e) m = fmaxf(m, v1[e]);
#pragma unroll
  for (int off = 32; off >= 1; off >>= 1) m = fmaxf(m, __shfl_xor(m, off));
  float s = 0.f;
#pragma unroll
  for (int e = 0; e < 4; ++e) { v0[e] = __expf(v0[e] - m); s += v0[e]; }
#pragma unroll
  for (int e = 0; e < 4; ++e) { v1[e] = __expf(v1[e] - m); s += v1[e]; }
#pragma unroll
  for (int off = 32; off >= 1; off >>= 1) s += __shfl_xor(s, off);
  const float inv = 1.f / s;
#pragma unroll
  for (int e = 0; e < 4; ++e) v0[e] *= inv;
#pragma unroll
  for (int e = 0; e < 4; ++e) v1[e] *= inv;
  *reinterpret_cast<f32x4*>(p) = v0;
  *reinterpret_cast<f32x4*>(p + 4) = v1;
}

// ---------------- PV: ctx[b,q,h*128+c] = sum_k P[q,k] * fv[b,h,k,c] ----------------
// P read directly from global f32 (each element used once), f_vT staged in LDS.
__global__ __launch_bounds__(256) void pv_kernel(const float* __restrict__ fr,
                                                 const __bf16* __restrict__ fvT,
                                                 __bf16* __restrict__ ctx) {
  __shared__ alignas(16) __bf16 Bs[128 * 64];
  const int tid = threadIdx.x;
  const int lane = tid & 63, wave = tid >> 6;
  const int wr = wave >> 1, wc = wave & 1;
  const int lr = lane & 15, lk = (lane >> 4) * 8;
  const int bh = blockIdx.y, b = bh >> 3, h = bh & 7;
  const int qt = blockIdx.x;
  const float* P = fr + (size_t)bh * 262144 + (size_t)qt * 128 * 512;
  const __bf16* Bb = fvT + (size_t)bh * 65536;
  f32x4 acc[4][4];
#pragma unroll
  for (int i = 0; i < 4; ++i)
#pragma unroll
    for (int j = 0; j < 4; ++j)
#pragma unroll
      for (int e = 0; e < 4; ++e) acc[i][j][e] = 0.f;
  const int sr = tid >> 3, sc = (tid & 7) * 8;

  for (int kt = 0; kt < 512; kt += 64) {
#pragma unroll
    for (int i = 0; i < 4; ++i)
      gload_lds16(Bb + (size_t)(sr + i * 32) * 512 + kt + sc, Bs + tid * 8 + i * 2048);
    __syncthreads();
#pragma unroll
    for (int kk = 0; kk < 64; kk += 32) {
      bf8 a[4], b[4];
#pragma unroll
      for (int mi = 0; mi < 4; ++mi) {
        const float* src = P + (size_t)(wr * 64 + mi * 16 + lr) * 512 + kt + kk + lk;
        f32x4 x0 = *reinterpret_cast<const f32x4*>(src);
        f32x4 x1 = *reinterpret_cast<const f32x4*>(src + 4);
        bf8 av;
        av[0] = (__bf16)x0[0]; av[1] = (__bf16)x0[1];
        av[2] = (__bf16)x0[2]; av[3] = (__bf16)x0[3];
        av[4] = (__bf16)x1[0]; av[5] = (__bf16)x1[1];
        av[6] = (__bf16)x1[2]; av[7] = (__bf16)x1[3];
        a[mi] = av;
      }
#pragma unroll
      for (int ni = 0; ni < 4; ++ni)
        b[ni] = *reinterpret_cast<const bf8*>(&Bs[(wc * 64 + ni * 16 + lr) * 64 + kk + lk]);
#pragma unroll
      for (int mi = 0; mi < 4; ++mi)
#pragma unroll
        for (int ni = 0; ni < 4; ++ni)
          acc[mi][ni] = __builtin_amdgcn_mfma_f32_16x16x32_bf16(a[mi], b[ni], acc[mi][ni], 0, 0, 0);
    }
    __syncthreads();
  }
#pragma unroll
  for (int mi = 0; mi < 4; ++mi) {
#pragma unroll
    for (int ni = 0; ni < 4; ++ni) {
      const int c = wc * 64 + ni * 16 + lr;
#pragma unroll
      for (int r = 0; r < 4; ++r) {
        const int q = qt * 128 + wr * 64 + mi * 16 + (lane >> 4) * 4 + r;
        ctx[(size_t)(b * 512 + q) * 1024 + h * 128 + c] = (__bf16)acc[mi][ni][r];
      }
    }
  }
}

extern "C" void kernel_launch(void* const* d_in, const int* in_sizes, int n_in,
                              void* d_out, int out_size, void* d_ws, size_t ws_size,
                              hipStream_t stream) {
  const float* x_q  = (const float*)d_in[0];
  const float* x_kv = (const float*)d_in[1];
  const float* Wh   = (const float*)d_in[2];
  const float* bh   = (const float*)d_in[3];
  const float* Wv   = (const float*)d_in[4];
  const float* bv   = (const float*)d_in[5];
  const float* Wo   = (const float*)d_in[6];
  const float* bo   = (const float*)d_in[7];
  const float* rel  = (const float*)d_in[8];
  const float* colh = (const float*)d_in[9];
  const float* colt = (const float*)d_in[10];

  float* out = (float*)d_out;
  float* fr  = out + 16777216;  // 32*512*1024 floats, then 256*512*512 floats

  __bf16* xq_bf  = (__bf16*)d_ws;
  __bf16* xkv_bf = xq_bf + 16777216;
  __bf16* Wh_bf  = xkv_bf + 16777216;
  __bf16* Wv_bf  = Wh_bf + 1048576;
  __bf16* Wo_bf  = Wv_bf + 1048576;
  __bf16* fhead  = Wo_bf + 1048576;
  __bf16* ftail  = fhead + 16777216;
  __bf16* fvT    = ftail + 16777216;
  float*  adjs   = (float*)(fvT + 16777216);
  __bf16* ctx    = (__bf16*)(adjs + 2097152);
  // total ws use: ~216 MB

  cvt_kernel<<<4096, 256, 0, stream>>>(x_q, xq_bf, 4194304);
  cvt_kernel<<<4096, 256, 0, stream>>>(x_kv, xkv_bf, 4194304);
  cvt_kernel<<<1024, 256, 0, stream>>>(Wh, Wh_bf, 262144);
  cvt_kernel<<<1024, 256, 0, stream>>>(Wv, Wv_bf, 262144);
  cvt_kernel<<<1024, 256, 0, stream>>>(Wo, Wo_bf, 262144);

  dim3 gp(8, 128);
  gemm_proj<0><<<gp, 256, 0, stream>>>(xq_bf, Wh_bf, bh, rel, fhead, nullptr);
  gemm_proj<0><<<gp, 256, 0, stream>>>(xkv_bf, Wh_bf, bh, rel, ftail, nullptr);
  gemm_proj<1><<<gp, 256, 0, stream>>>(xkv_bf, Wv_bf, bv, nullptr, fvT, nullptr);

  adj_kernel<<<1024, 256, 0, stream>>>(colh, colt, adjs);

  scores_kernel<<<dim3(4, 4, 256), 256, 0, stream>>>(fhead, ftail, adjs, fr);
  softmax_kernel<<<32768, 256, 0, stream>>>(fr);
  pv_kernel<<<dim3(4, 256), 256, 0, stream>>>(fr, fvT, ctx);

  gemm_proj<2><<<gp, 256, 0, stream>>>(ctx, Wo_bf, bo, nullptr, nullptr, out);
}

// Round 2
// 899.991 us; speedup vs baseline: 1.0378x; 1.0378x over previous
//
#include <hip/hip_runtime.h>

typedef __attribute__((ext_vector_type(8))) __bf16 bf8;
typedef __attribute__((ext_vector_type(4))) __bf16 bf4;
typedef __attribute__((ext_vector_type(4))) float f32x4;

#define DEVI static __device__ __forceinline__

// async global->LDS, 16B per lane. LDS dest must be linear in lane order.
DEVI void gload_lds16(const void* g, void* l) {
  __builtin_amdgcn_global_load_lds(
      (const __attribute__((address_space(1))) unsigned int*)g,
      (__attribute__((address_space(3))) unsigned int*)l, 16, 0, 0);
}

// ---------------- f32 -> bf16 convert ----------------
__global__ __launch_bounds__(256) void cvt_kernel(const float* __restrict__ in,
                                                  __bf16* __restrict__ out, int n4) {
  int stride = gridDim.x * blockDim.x;
  for (int i = blockIdx.x * blockDim.x + threadIdx.x; i < n4; i += stride) {
    f32x4 v = reinterpret_cast<const f32x4*>(in)[i];
    bf4 o;
    o[0] = (__bf16)v[0]; o[1] = (__bf16)v[1]; o[2] = (__bf16)v[2]; o[3] = (__bf16)v[3];
    reinterpret_cast<bf4*>(out)[i] = o;
  }
}

// ---------------- generic projection GEMM ----------------
// C[m][n] = sum_k A[m][k] * Bw[n][k]  (+bias[n]) ; M=16384, N=1024, K=1024
// MODE 0: out bf16, *= rel[n], heads layout  [b,h,q,c]
// MODE 1: out bf16, transposed heads layout  [b,h,c,q]   (f_v -> f_vT)
// MODE 2: out f32 flat [m*1024+n]
template <int MODE>
__global__ __launch_bounds__(256) void gemm_proj(
    const __bf16* __restrict__ A, const __bf16* __restrict__ Bw,
    const float* __restrict__ bias, const float* __restrict__ rel,
    __bf16* __restrict__ obf, float* __restrict__ of32) {
  __shared__ alignas(16) __bf16 As[128 * 64];
  __shared__ alignas(16) __bf16 Bs[128 * 64];
  const int tid = threadIdx.x;
  const int lane = tid & 63;
  const int wave = tid >> 6;
  const int wr = wave >> 1, wc = wave & 1;
  const int lr = lane & 15, lk = (lane >> 4) * 8;

  f32x4 acc[4][4];
#pragma unroll
  for (int i = 0; i < 4; ++i)
#pragma unroll
    for (int j = 0; j < 4; ++j)
#pragma unroll
      for (int e = 0; e < 4; ++e) acc[i][j][e] = 0.f;

  const __bf16* Ab = A + (size_t)blockIdx.y * 128 * 1024;
  const __bf16* Bb = Bw + (size_t)blockIdx.x * 128 * 1024;
  const int sr = tid >> 3;
  const int sc = (tid & 7) * 8;

  for (int kt = 0; kt < 1024; kt += 64) {
#pragma unroll
    for (int i = 0; i < 4; ++i) {
      gload_lds16(Ab + (size_t)(sr + i * 32) * 1024 + kt + sc, As + tid * 8 + i * 2048);
      gload_lds16(Bb + (size_t)(sr + i * 32) * 1024 + kt + sc, Bs + tid * 8 + i * 2048);
    }
    __syncthreads();
#pragma unroll
    for (int kk = 0; kk < 64; kk += 32) {
      bf8 a[4], b[4];
#pragma unroll
      for (int mi = 0; mi < 4; ++mi)
        a[mi] = *reinterpret_cast<const bf8*>(&As[(wr * 64 + mi * 16 + lr) * 64 + kk + lk]);
#pragma unroll
      for (int ni = 0; ni < 4; ++ni)
        b[ni] = *reinterpret_cast<const bf8*>(&Bs[(wc * 64 + ni * 16 + lr) * 64 + kk + lk]);
#pragma unroll
      for (int mi = 0; mi < 4; ++mi)
#pragma unroll
        for (int ni = 0; ni < 4; ++ni)
          acc[mi][ni] = __builtin_amdgcn_mfma_f32_16x16x32_bf16(a[mi], b[ni], acc[mi][ni], 0, 0, 0);
    }
    __syncthreads();
  }

  const int mBase = blockIdx.y * 128 + wr * 64;
  const int nBase = blockIdx.x * 128 + wc * 64;
#pragma unroll
  for (int mi = 0; mi < 4; ++mi) {
#pragma unroll
    for (int ni = 0; ni < 4; ++ni) {
      const int n = nBase + ni * 16 + lr;
#pragma unroll
      for (int r = 0; r < 4; ++r) {
        const int m = mBase + mi * 16 + (lane >> 4) * 4 + r;
        float v = acc[mi][ni][r] + bias[n];
        if (MODE == 0) v *= rel[n];
        if (MODE == 2) {
          of32[(size_t)m * 1024 + n] = v;
        } else if (MODE == 0) {
          size_t idx = ((size_t)((m >> 9) * 8 + (n >> 7))) * 65536 +
                       (size_t)(m & 511) * 128 + (n & 127);
          obf[idx] = (__bf16)v;
        } else {
          size_t idx = ((size_t)((m >> 9) * 8 + (n >> 7))) * 65536 +
                       (size_t)(n & 127) * 512 + (m & 511);
          obf[idx] = (__bf16)v;
        }
      }
    }
  }
}

// ---------------- adj: per-head column softmax, scaled by 1e4 ----------------
__global__ __launch_bounds__(256) void adj_kernel(const float* __restrict__ ch_all,
                                                  const float* __restrict__ ct_all,
                                                  float* __restrict__ adjs) {
  const int wave = threadIdx.x >> 6, lane = threadIdx.x & 63;
  const int row = blockIdx.x * 4 + wave;  // 0..4095
  const int h = row >> 9, i = row & 511;
  float ch[18];
  const float* chp = ch_all + ((size_t)h * 512 + i) * 18;
#pragma unroll
  for (int t = 0; t < 18; ++t) ch[t] = chp[t];
  float e[8];
  float m = -1e30f;
#pragma unroll
  for (int jj = 0; jj < 8; ++jj) {
    const int j = jj * 64 + lane;
    const float* ctp = ct_all + ((size_t)h * 512 + j) * 18;
    float d = 0.f;
#pragma unroll
    for (int t = 0; t < 18; ++t) d += ch[t] * ctp[t];
    if (j == i) d = 0.f;
    e[jj] = d;
    m = fmaxf(m, d);
  }
#pragma unroll
  for (int off = 32; off >= 1; off >>= 1) m = fmaxf(m, __shfl_xor(m, off));
  float s = 0.f;
#pragma unroll
  for (int jj = 0; jj < 8; ++jj) { e[jj] = __expf(e[jj] - m); s += e[jj]; }
#pragma unroll
  for (int off = 32; off >= 1; off >>= 1) s += __shfl_xor(s, off);
  const float inv = 10000.f / s;
  float* op = adjs + (size_t)h * 262144 + (size_t)i * 512;
#pragma unroll
  for (int jj = 0; jj < 8; ++jj) op[jj * 64 + lane] = e[jj] * inv;
}

// ---------------- fused attention core: scores + row-softmax + PV ----------------
// Block = 256 thr (4 waves), owns 64 q-rows x all 512 k for one (b,h).
// Wave w owns q-rows [qt*64 + w*16, +16), holds S strip 16x512 in regs.
// Phase 1: S = fh . ft^T  (A-frags from global, ft tiles LDS-staged)
// Phase 2: logits = S/sqrt(128) + adjs; in-register row softmax; write fr (f32)
// Phase 3: PV: A-frags = read own P back from fr (L2-hot), V tiles LDS-staged
__global__ __launch_bounds__(256) void fused_attn_kernel(
    const __bf16* __restrict__ fh, const __bf16* __restrict__ ft,
    const __bf16* __restrict__ fvT, const float* __restrict__ adjs,
    float* fr, __bf16* __restrict__ ctx) {
  __shared__ alignas(16) __bf16 Bt[128 * 128];  // 32 KB, reused by phases 1 & 3
  const int tid = threadIdx.x;
  const int l = tid & 63, w = tid >> 6;
  const int qt = blockIdx.x;       // 0..7
  const int bh = blockIdx.y;       // 0..255
  const int b = bh >> 3, h = bh & 7;
  const int wrow = qt * 64 + w * 16;
  const int lr = l & 15, lk = (l >> 4) * 8;

  // A fragments: wave's own 16 rows x 128 c of fh, straight from global.
  bf8 afr[4];
  {
    const __bf16* ap = fh + (size_t)bh * 65536 + (size_t)(wrow + lr) * 128 + lk;
#pragma unroll
    for (int kk4 = 0; kk4 < 4; ++kk4)
      afr[kk4] = *reinterpret_cast<const bf8*>(ap + kk4 * 32);
  }

  f32x4 acc[32];
#pragma unroll
  for (int n = 0; n < 32; ++n)
#pragma unroll
    for (int e = 0; e < 4; ++e) acc[n][e] = 0.f;

  const __bf16* ftb = ft + (size_t)bh * 65536;
#pragma unroll
  for (int kt = 0; kt < 4; ++kt) {
    __syncthreads();
#pragma unroll
    for (int i = 0; i < 8; ++i)
      gload_lds16(ftb + (size_t)(kt * 128 + i * 16 + (tid >> 4)) * 128 + (tid & 15) * 8,
                  Bt + i * 2048 + tid * 8);
    __syncthreads();
#pragma unroll
    for (int kk4 = 0; kk4 < 4; ++kk4) {
      bf8 bfr[8];
#pragma unroll
      for (int n2 = 0; n2 < 8; ++n2)
        bfr[n2] = *reinterpret_cast<const bf8*>(&Bt[(n2 * 16 + lr) * 128 + kk4 * 32 + lk]);
#pragma unroll
      for (int n2 = 0; n2 < 8; ++n2)
        acc[kt * 8 + n2] =
            __builtin_amdgcn_mfma_f32_16x16x32_bf16(afr[kk4], bfr[n2], acc[kt * 8 + n2], 0, 0, 0);
    }
  }

  // ---- phase 2: logits + in-register row softmax ----
  const float scale = 0.08838834764831845f;  // 1/sqrt(128)
  const float* adjp = adjs + (size_t)h * 262144;
  float mrow[4] = {-1e30f, -1e30f, -1e30f, -1e30f};
#pragma unroll
  for (int n = 0; n < 32; ++n) {
    const int col = n * 16 + lr;
#pragma unroll
    for (int r = 0; r < 4; ++r) {
      const int q = wrow + (l >> 4) * 4 + r;
      float v = acc[n][r] * scale + adjp[(size_t)q * 512 + col];
      acc[n][r] = v;
      mrow[r] = fmaxf(mrow[r], v);
    }
  }
#pragma unroll
  for (int r = 0; r < 4; ++r)
#pragma unroll
    for (int off = 1; off <= 8; off <<= 1) mrow[r] = fmaxf(mrow[r], __shfl_xor(mrow[r], off));
  float srow[4] = {0.f, 0.f, 0.f, 0.f};
#pragma unroll
  for (int n = 0; n < 32; ++n)
#pragma unroll
    for (int r = 0; r < 4; ++r) {
      float e = __expf(acc[n][r] - mrow[r]);
      acc[n][r] = e;
      srow[r] += e;
    }
#pragma unroll
  for (int r = 0; r < 4; ++r)
#pragma unroll
    for (int off = 1; off <= 8; off <<= 1) srow[r] += __shfl_xor(srow[r], off);
  float inv[4];
#pragma unroll
  for (int r = 0; r < 4; ++r) inv[r] = 1.f / srow[r];

  float* frb = fr + (size_t)bh * 262144;
#pragma unroll
  for (int n = 0; n < 32; ++n) {
    const int col = n * 16 + lr;
#pragma unroll
    for (int r = 0; r < 4; ++r) {
      const int q = wrow + (l >> 4) * 4 + r;
      acc[n][r] *= inv[r];
      frb[(size_t)q * 512 + col] = acc[n][r];
    }
  }

  // ---- phase 3: PV ----
  f32x4 acc2[8];
#pragma unroll
  for (int n2 = 0; n2 < 8; ++n2)
#pragma unroll
    for (int e = 0; e < 4; ++e) acc2[n2][e] = 0.f;

  const __bf16* fvb = fvT + (size_t)bh * 65536;
  const float* frr = fr + (size_t)bh * 262144 + (size_t)(wrow + lr) * 512;
  asm volatile("s_waitcnt vmcnt(0)" ::: "memory");  // own P stores visible before readback
#pragma unroll
  for (int kt = 0; kt < 4; ++kt) {
    __syncthreads();
#pragma unroll
    for (int i = 0; i < 8; ++i)
      gload_lds16(fvb + (size_t)(i * 16 + (tid >> 4)) * 512 + kt * 128 + (tid & 15) * 8,
                  Bt + i * 2048 + tid * 8);
    __syncthreads();
#pragma unroll
    for (int kk4 = 0; kk4 < 4; ++kk4) {
      const float* src = frr + kt * 128 + kk4 * 32 + lk;
      f32x4 x0 = *reinterpret_cast<const f32x4*>(src);
      f32x4 x1 = *reinterpret_cast<const f32x4*>(src + 4);
      bf8 av;
      av[0] = (__bf16)x0[0]; av[1] = (__bf16)x0[1];
      av[2] = (__bf16)x0[2]; av[3] = (__bf16)x0[3];
      av[4] = (__bf16)x1[0]; av[5] = (__bf16)x1[1];
      av[6] = (__bf16)x1[2]; av[7] = (__bf16)x1[3];
      bf8 bfr[8];
#pragma unroll
      for (int n2 = 0; n2 < 8; ++n2)
        bfr[n2] = *reinterpret_cast<const bf8*>(&Bt[(n2 * 16 + lr) * 128 + kk4 * 32 + lk]);
#pragma unroll
      for (int n2 = 0; n2 < 8; ++n2)
        acc2[n2] = __builtin_amdgcn_mfma_f32_16x16x32_bf16(av, bfr[n2], acc2[n2], 0, 0, 0);
    }
  }
#pragma unroll
  for (int n2 = 0; n2 < 8; ++n2) {
    const int c = n2 * 16 + lr;
#pragma unroll
    for (int r = 0; r < 4; ++r) {
      const int q = wrow + (l >> 4) * 4 + r;
      ctx[(size_t)(b * 512 + q) * 1024 + h * 128 + c] = (__bf16)acc2[n2][r];
    }
  }
}

extern "C" void kernel_launch(void* const* d_in, const int* in_sizes, int n_in,
                              void* d_out, int out_size, void* d_ws, size_t ws_size,
                              hipStream_t stream) {
  const float* x_q  = (const float*)d_in[0];
  const float* x_kv = (const float*)d_in[1];
  const float* Wh   = (const float*)d_in[2];
  const float* bh   = (const float*)d_in[3];
  const float* Wv   = (const float*)d_in[4];
  const float* bv   = (const float*)d_in[5];
  const float* Wo   = (const float*)d_in[6];
  const float* bo   = (const float*)d_in[7];
  const float* rel  = (const float*)d_in[8];
  const float* colh = (const float*)d_in[9];
  const float* colt = (const float*)d_in[10];

  float* out = (float*)d_out;
  float* fr  = out + 16777216;  // 32*512*1024 floats, then 256*512*512 floats

  __bf16* xq_bf  = (__bf16*)d_ws;
  __bf16* xkv_bf = xq_bf + 16777216;
  __bf16* Wh_bf  = xkv_bf + 16777216;
  __bf16* Wv_bf  = Wh_bf + 1048576;
  __bf16* Wo_bf  = Wv_bf + 1048576;
  __bf16* fhead  = Wo_bf + 1048576;
  __bf16* ftail  = fhead + 16777216;
  __bf16* fvT    = ftail + 16777216;
  float*  adjs   = (float*)(fvT + 16777216);
  __bf16* ctx    = (__bf16*)(adjs + 2097152);

  cvt_kernel<<<4096, 256, 0, stream>>>(x_q, xq_bf, 4194304);
  cvt_kernel<<<4096, 256, 0, stream>>>(x_kv, xkv_bf, 4194304);
  cvt_kernel<<<1024, 256, 0, stream>>>(Wh, Wh_bf, 262144);
  cvt_kernel<<<1024, 256, 0, stream>>>(Wv, Wv_bf, 262144);
  cvt_kernel<<<1024, 256, 0, stream>>>(Wo, Wo_bf, 262144);

  dim3 gp(8, 128);
  gemm_proj<0><<<gp, 256, 0, stream>>>(xq_bf, Wh_bf, bh, rel, fhead, nullptr);
  gemm_proj<0><<<gp, 256, 0, stream>>>(xkv_bf, Wh_bf, bh, rel, ftail, nullptr);
  gemm_proj<1><<<gp, 256, 0, stream>>>(xkv_bf, Wv_bf, bv, nullptr, fvT, nullptr);

  adj_kernel<<<1024, 256, 0, stream>>>(colh, colt, adjs);

  fused_attn_kernel<<<dim3(8, 256), 256, 0, stream>>>(fhead, ftail, fvT, adjs, fr, ctx);

  gemm_proj<2><<<gp, 256, 0, stream>>>(ctx, Wo_bf, bo, nullptr, nullptr, out);
}

// Round 3
// 895.487 us; speedup vs baseline: 1.0431x; 1.0050x over previous
//
#include <hip/hip_runtime.h>

typedef __attribute__((ext_vector_type(8))) __bf16 bf8;
typedef __attribute__((ext_vector_type(4))) __bf16 bf4;
typedef __attribute__((ext_vector_type(4))) float f32x4;

#define DEVI static __device__ __forceinline__

// async global->LDS, 16B per lane. LDS dest must be linear in lane order.
DEVI void gload_lds16(const void* g, void* l) {
  __builtin_amdgcn_global_load_lds(
      (const __attribute__((address_space(1))) unsigned int*)g,
      (__attribute__((address_space(3))) unsigned int*)l, 16, 0, 0);
}

// ---------------- f32 -> bf16 convert ----------------
__global__ __launch_bounds__(256) void cvt_kernel(const float* __restrict__ in,
                                                  __bf16* __restrict__ out, int n4) {
  int stride = gridDim.x * blockDim.x;
  for (int i = blockIdx.x * blockDim.x + threadIdx.x; i < n4; i += stride) {
    f32x4 v = reinterpret_cast<const f32x4*>(in)[i];
    bf4 o;
    o[0] = (__bf16)v[0]; o[1] = (__bf16)v[1]; o[2] = (__bf16)v[2]; o[3] = (__bf16)v[3];
    reinterpret_cast<bf4*>(out)[i] = o;
  }
}

// ---------------- generic projection GEMM ----------------
// C[m][n] = sum_k A[m][k] * Bw[n][k]  (+bias[n]) ; M=16384, N=1024, K=1024
// grid = (128 m-tiles, 8 n-tiles): XCD = m-tile % 8 -> A-panel L2 affinity.
template <int MODE>
__global__ __launch_bounds__(256) void gemm_proj(
    const __bf16* __restrict__ A, const __bf16* __restrict__ Bw,
    const float* __restrict__ bias, const float* __restrict__ rel,
    __bf16* __restrict__ obf, float* __restrict__ of32) {
  __shared__ alignas(16) __bf16 As[128 * 64];
  __shared__ alignas(16) __bf16 Bs[128 * 64];
  const int tid = threadIdx.x;
  const int lane = tid & 63;
  const int wave = tid >> 6;
  const int wr = wave >> 1, wc = wave & 1;
  const int lr = lane & 15, lk = (lane >> 4) * 8;
  const int bm = blockIdx.x, bn = blockIdx.y;

  f32x4 acc[4][4];
#pragma unroll
  for (int i = 0; i < 4; ++i)
#pragma unroll
    for (int j = 0; j < 4; ++j)
#pragma unroll
      for (int e = 0; e < 4; ++e) acc[i][j][e] = 0.f;

  const __bf16* Ab = A + (size_t)bm * 128 * 1024;
  const __bf16* Bb = Bw + (size_t)bn * 128 * 1024;
  const int sr = tid >> 3;
  const int sc = (tid & 7) * 8;

  for (int kt = 0; kt < 1024; kt += 64) {
#pragma unroll
    for (int i = 0; i < 4; ++i) {
      gload_lds16(Ab + (size_t)(sr + i * 32) * 1024 + kt + sc, As + tid * 8 + i * 2048);
      gload_lds16(Bb + (size_t)(sr + i * 32) * 1024 + kt + sc, Bs + tid * 8 + i * 2048);
    }
    __syncthreads();
#pragma unroll
    for (int kk = 0; kk < 64; kk += 32) {
      bf8 a[4], b[4];
#pragma unroll
      for (int mi = 0; mi < 4; ++mi)
        a[mi] = *reinterpret_cast<const bf8*>(&As[(wr * 64 + mi * 16 + lr) * 64 + kk + lk]);
#pragma unroll
      for (int ni = 0; ni < 4; ++ni)
        b[ni] = *reinterpret_cast<const bf8*>(&Bs[(wc * 64 + ni * 16 + lr) * 64 + kk + lk]);
#pragma unroll
      for (int mi = 0; mi < 4; ++mi)
#pragma unroll
        for (int ni = 0; ni < 4; ++ni)
          acc[mi][ni] = __builtin_amdgcn_mfma_f32_16x16x32_bf16(a[mi], b[ni], acc[mi][ni], 0, 0, 0);
    }
    __syncthreads();
  }

  const int mBase = bm * 128 + wr * 64;
  const int nBase = bn * 128 + wc * 64;
#pragma unroll
  for (int mi = 0; mi < 4; ++mi) {
#pragma unroll
    for (int ni = 0; ni < 4; ++ni) {
      const int n = nBase + ni * 16 + lr;
#pragma unroll
      for (int r = 0; r < 4; ++r) {
        const int m = mBase + mi * 16 + (lane >> 4) * 4 + r;
        float v = acc[mi][ni][r] + bias[n];
        if (MODE == 0) v *= rel[n];
        if (MODE == 2) {
          of32[(size_t)m * 1024 + n] = v;
        } else if (MODE == 0) {
          size_t idx = ((size_t)((m >> 9) * 8 + (n >> 7))) * 65536 +
                       (size_t)(m & 511) * 128 + (n & 127);
          obf[idx] = (__bf16)v;
        } else {
          size_t idx = ((size_t)((m >> 9) * 8 + (n >> 7))) * 65536 +
                       (size_t)(n & 127) * 512 + (m & 511);
          obf[idx] = (__bf16)v;
        }
      }
    }
  }
}

// ---------------- adj: per-head column softmax, scaled by 1e4, TRANSPOSED out ----------------
// adjT[h][j][i] = 10000 * softmax_j( (j==i) ? 0 : dot18(col_head[h,i], col_tail[h,j]) )
__global__ __launch_bounds__(256) void adj_kernel(const float* __restrict__ ch_all,
                                                  const float* __restrict__ ct_all,
                                                  float* __restrict__ adjT) {
  const int wave = threadIdx.x >> 6, lane = threadIdx.x & 63;
  const int row = blockIdx.x * 4 + wave;  // 0..4095
  const int h = row >> 9, i = row & 511;
  float ch[18];
  const float* chp = ch_all + ((size_t)h * 512 + i) * 18;
#pragma unroll
  for (int t = 0; t < 18; ++t) ch[t] = chp[t];
  float e[8];
  float m = -1e30f;
#pragma unroll
  for (int jj = 0; jj < 8; ++jj) {
    const int j = jj * 64 + lane;
    const float* ctp = ct_all + ((size_t)h * 512 + j) * 18;
    float d = 0.f;
#pragma unroll
    for (int t = 0; t < 18; ++t) d += ch[t] * ctp[t];
    if (j == i) d = 0.f;
    e[jj] = d;
    m = fmaxf(m, d);
  }
#pragma unroll
  for (int off = 32; off >= 1; off >>= 1) m = fmaxf(m, __shfl_xor(m, off));
  float s = 0.f;
#pragma unroll
  for (int jj = 0; jj < 8; ++jj) { e[jj] = __expf(e[jj] - m); s += e[jj]; }
#pragma unroll
  for (int off = 32; off >= 1; off >>= 1) s += __shfl_xor(s, off);
  const float inv = 10000.f / s;
  float* op = adjT + (size_t)h * 262144 + i;  // column i of [512][512]
#pragma unroll
  for (int jj = 0; jj < 8; ++jj) op[(size_t)(jj * 64 + lane) * 512] = e[jj] * inv;
}

// ---------------- fused attention core: scores + row-softmax + PV ----------------
// Block = 4 waves, owns 64 q x 512 k of one (b,h). grid x=bh (XCD=h), y=qt.
// S strip per wave: 16q x 512k in acc[32] (C-layout).
// ft/fv tiles staged with XOR-chunk swizzle (linear LDS dest, pre-swizzled
// global source, swizzled ds_read) -> conflict-free B-frag reads.
// P never round-trips through global: per 128-col chunk, bounce through a
// 4KB per-wave swizzled LDS buffer to convert C-layout -> A-frag layout.
__global__ __launch_bounds__(256, 3) void fused_attn_kernel(
    const __bf16* __restrict__ fh, const __bf16* __restrict__ ft,
    const __bf16* __restrict__ fvT, const float* __restrict__ adjT,
    float* __restrict__ fr, __bf16* __restrict__ ctx) {
  __shared__ alignas(16) __bf16 Bt[128 * 128];    // 32 KB staging (ft / fv tiles)
  __shared__ alignas(16) __bf16 Pl[4][16 * 128];  // 16 KB, per-wave P chunk
  const int tid = threadIdx.x;
  const int l = tid & 63, w = tid >> 6;
  const int bh = blockIdx.x;  // 0..255 -> XCD = bh&7 = h
  const int qt = blockIdx.y;  // 0..7
  const int b = bh >> 3, h = bh & 7;
  const int wrow = qt * 64 + w * 16;
  const int lr = l & 15;
  const int khi = l >> 4;  // 0..3

  // staging source pre-swizzle: LDS[row][cc] <- G[row][cc ^ (row&7)]
  const int srow = tid >> 4;                 // row within 16-row group
  const int scc = (tid & 15) ^ (srow & 7);   // source chunk

  // A fragments for QK^T: wave's own 16 rows of fh
  bf8 afr[4];
  {
    const __bf16* ap = fh + (size_t)bh * 65536 + (size_t)(wrow + lr) * 128 + khi * 8;
#pragma unroll
    for (int kk4 = 0; kk4 < 4; ++kk4)
      afr[kk4] = *reinterpret_cast<const bf8*>(ap + kk4 * 32);
  }

  f32x4 acc[32];
#pragma unroll
  for (int n = 0; n < 32; ++n)
#pragma unroll
    for (int e = 0; e < 4; ++e) acc[n][e] = 0.f;

  // ---- phase 1: S = fh . ft^T ----
  const __bf16* ftb = ft + (size_t)bh * 65536;
#pragma unroll
  for (int kt = 0; kt < 4; ++kt) {
#pragma unroll
    for (int i = 0; i < 8; ++i)
      gload_lds16(ftb + (size_t)(kt * 128 + i * 16 + srow) * 128 + scc * 8,
                  Bt + i * 2048 + tid * 8);
    __syncthreads();
#pragma unroll
    for (int kk4 = 0; kk4 < 4; ++kk4) {
      bf8 bfr[8];
#pragma unroll
      for (int n2 = 0; n2 < 8; ++n2)
        bfr[n2] = *reinterpret_cast<const bf8*>(
            &Bt[(n2 * 16 + lr) * 128 + ((kk4 * 4 + khi) ^ (lr & 7)) * 8]);
#pragma unroll
      for (int n2 = 0; n2 < 8; ++n2)
        acc[kt * 8 + n2] =
            __builtin_amdgcn_mfma_f32_16x16x32_bf16(afr[kk4], bfr[n2], acc[kt * 8 + n2], 0, 0, 0);
    }
    __syncthreads();
  }

  // ---- phase 2: logits = S/sqrt(128) + adjT; in-register row softmax ----
  const float scale = 0.08838834764831845f;  // 1/sqrt(128)
  const float* adjTp = adjT + (size_t)h * 262144;
  float mrow[4] = {-1e30f, -1e30f, -1e30f, -1e30f};
#pragma unroll
  for (int n = 0; n < 32; ++n) {
    const int col = n * 16 + lr;
    f32x4 av = *reinterpret_cast<const f32x4*>(adjTp + (size_t)col * 512 + wrow + khi * 4);
#pragma unroll
    for (int r = 0; r < 4; ++r) {
      float v = acc[n][r] * scale + av[r];
      acc[n][r] = v;
      mrow[r] = fmaxf(mrow[r], v);
    }
  }
#pragma unroll
  for (int r = 0; r < 4; ++r)
#pragma unroll
    for (int off = 1; off <= 8; off <<= 1) mrow[r] = fmaxf(mrow[r], __shfl_xor(mrow[r], off));
  float srw[4] = {0.f, 0.f, 0.f, 0.f};
#pragma unroll
  for (int n = 0; n < 32; ++n)
#pragma unroll
    for (int r = 0; r < 4; ++r) {
      float e = __expf(acc[n][r] - mrow[r]);
      acc[n][r] = e;
      srw[r] += e;
    }
#pragma unroll
  for (int r = 0; r < 4; ++r)
#pragma unroll
    for (int off = 1; off <= 8; off <<= 1) srw[r] += __shfl_xor(srw[r], off);
  float inv[4];
#pragma unroll
  for (int r = 0; r < 4; ++r) inv[r] = 1.f / srw[r];
#pragma unroll
  for (int n = 0; n < 32; ++n)
#pragma unroll
    for (int r = 0; r < 4; ++r) acc[n][r] *= inv[r];

  // prefetch fv tile 0 (Bt free: last QK barrier passed); overlaps fr writes
  const __bf16* fvb = fvT + (size_t)bh * 65536;
#pragma unroll
  for (int i = 0; i < 8; ++i)
    gload_lds16(fvb + (size_t)(i * 16 + srow) * 512 + scc * 8, Bt + i * 2048 + tid * 8);

  // write fr (required output), once
  {
    float* frb = fr + (size_t)bh * 262144;
#pragma unroll
    for (int n = 0; n < 32; ++n) {
      const int col = n * 16 + lr;
#pragma unroll
      for (int r = 0; r < 4; ++r)
        frb[(size_t)(wrow + khi * 4 + r) * 512 + col] = acc[n][r];
    }
  }

  // ---- phase 3: PV via per-wave LDS bounce of P chunks ----
  f32x4 acc2[8];
#pragma unroll
  for (int n2 = 0; n2 < 8; ++n2)
#pragma unroll
    for (int e = 0; e < 4; ++e) acc2[n2][e] = 0.f;

  __bf16* Pw = &Pl[w][0];
#pragma unroll
  for (int kt = 0; kt < 4; ++kt) {
    // bounce own P chunk kt into swizzled per-wave LDS (C-layout -> A-frag layout)
#pragma unroll
    for (int n2 = 0; n2 < 8; ++n2) {
      const int colc = n2 * 2 + (lr >> 3);  // logical chunk = col>>3
      const int cl = lr & 7;
#pragma unroll
      for (int r = 0; r < 4; ++r) {
        const int q = khi * 4 + r;
        Pw[q * 128 + ((colc ^ (q & 7)) * 8) + cl] = (__bf16)acc[kt * 8 + n2][r];
      }
    }
    __syncthreads();  // fv(kt) staged (vmcnt) + P writes done (lgkm)
#pragma unroll
    for (int kk4 = 0; kk4 < 4; ++kk4) {
      bf8 pa = *reinterpret_cast<const bf8*>(
          &Pw[lr * 128 + ((kk4 * 4 + khi) ^ (lr & 7)) * 8]);
      bf8 bfr[8];
#pragma unroll
      for (int n2 = 0; n2 < 8; ++n2)
        bfr[n2] = *reinterpret_cast<const bf8*>(
            &Bt[(n2 * 16 + lr) * 128 + ((kk4 * 4 + khi) ^ (lr & 7)) * 8]);
#pragma unroll
      for (int n2 = 0; n2 < 8; ++n2)
        acc2[n2] = __builtin_amdgcn_mfma_f32_16x16x32_bf16(pa, bfr[n2], acc2[n2], 0, 0, 0);
    }
    __syncthreads();  // all reads of Bt(kt) done
    if (kt < 3) {
      const int ktn = kt + 1;
#pragma unroll
      for (int i = 0; i < 8; ++i)
        gload_lds16(fvb + (size_t)(i * 16 + srow) * 512 + ktn * 128 + scc * 8,
                    Bt + i * 2048 + tid * 8);
    }
  }

#pragma unroll
  for (int n2 = 0; n2 < 8; ++n2) {
    const int c = n2 * 16 + lr;
#pragma unroll
    for (int r = 0; r < 4; ++r) {
      const int q = wrow + khi * 4 + r;
      ctx[(size_t)(b * 512 + q) * 1024 + h * 128 + c] = (__bf16)acc2[n2][r];
    }
  }
}

extern "C" void kernel_launch(void* const* d_in, const int* in_sizes, int n_in,
                              void* d_out, int out_size, void* d_ws, size_t ws_size,
                              hipStream_t stream) {
  const float* x_q  = (const float*)d_in[0];
  const float* x_kv = (const float*)d_in[1];
  const float* Wh   = (const float*)d_in[2];
  const float* bh   = (const float*)d_in[3];
  const float* Wv   = (const float*)d_in[4];
  const float* bv   = (const float*)d_in[5];
  const float* Wo   = (const float*)d_in[6];
  const float* bo   = (const float*)d_in[7];
  const float* rel  = (const float*)d_in[8];
  const float* colh = (const float*)d_in[9];
  const float* colt = (const float*)d_in[10];

  float* out = (float*)d_out;
  float* fr  = out + 16777216;  // 32*512*1024 floats, then 256*512*512 floats

  __bf16* xq_bf  = (__bf16*)d_ws;
  __bf16* xkv_bf = xq_bf + 16777216;
  __bf16* Wh_bf  = xkv_bf + 16777216;
  __bf16* Wv_bf  = Wh_bf + 1048576;
  __bf16* Wo_bf  = Wv_bf + 1048576;
  __bf16* fhead  = Wo_bf + 1048576;
  __bf16* ftail  = fhead + 16777216;
  __bf16* fvT    = ftail + 16777216;
  float*  adjT   = (float*)(fvT + 16777216);
  __bf16* ctx    = (__bf16*)(adjT + 2097152);

  cvt_kernel<<<4096, 256, 0, stream>>>(x_q, xq_bf, 4194304);
  cvt_kernel<<<4096, 256, 0, stream>>>(x_kv, xkv_bf, 4194304);
  cvt_kernel<<<1024, 256, 0, stream>>>(Wh, Wh_bf, 262144);
  cvt_kernel<<<1024, 256, 0, stream>>>(Wv, Wv_bf, 262144);
  cvt_kernel<<<1024, 256, 0, stream>>>(Wo, Wo_bf, 262144);

  dim3 gp(128, 8);
  gemm_proj<0><<<gp, 256, 0, stream>>>(xq_bf, Wh_bf, bh, rel, fhead, nullptr);
  gemm_proj<0><<<gp, 256, 0, stream>>>(xkv_bf, Wh_bf, bh, rel, ftail, nullptr);
  gemm_proj<1><<<gp, 256, 0, stream>>>(xkv_bf, Wv_bf, bv, nullptr, fvT, nullptr);

  adj_kernel<<<1024, 256, 0, stream>>>(colh, colt, adjT);

  fused_attn_kernel<<<dim3(256, 8), 256, 0, stream>>>(fhead, ftail, fvT, adjT, fr, ctx);

  gemm_proj<2><<<gp, 256, 0, stream>>>(ctx, Wo_bf, bo, nullptr, nullptr, out);
}

// Round 7
// 878.127 us; speedup vs baseline: 1.0637x; 1.0198x over previous
//
#include <hip/hip_runtime.h>

typedef __attribute__((ext_vector_type(8))) __bf16 bf8;
typedef __attribute__((ext_vector_type(4))) __bf16 bf4;
typedef __attribute__((ext_vector_type(4))) float f32x4;

#define DEVI static __device__ __forceinline__

// async global->LDS, 16B per lane. LDS dest must be linear in lane order.
DEVI void gload_lds16(const void* g, void* l) {
  __builtin_amdgcn_global_load_lds(
      (const __attribute__((address_space(1))) unsigned int*)g,
      (__attribute__((address_space(3))) unsigned int*)l, 16, 0, 0);
}

// ---------------- f32 -> bf16 convert ----------------
__global__ __launch_bounds__(256) void cvt_kernel(const float* __restrict__ in,
                                                  __bf16* __restrict__ out, int n4) {
  int stride = gridDim.x * blockDim.x;
  for (int i = blockIdx.x * blockDim.x + threadIdx.x; i < n4; i += stride) {
    f32x4 v = reinterpret_cast<const f32x4*>(in)[i];
    bf4 o;
    o[0] = (__bf16)v[0]; o[1] = (__bf16)v[1]; o[2] = (__bf16)v[2]; o[3] = (__bf16)v[3];
    reinterpret_cast<bf4*>(out)[i] = o;
  }
}

// ---------------- generic projection GEMM ----------------
// C[m][n] = sum_k A[m][k] * Bw[n][k]  (+bias[n]) ; M=16384, N=1024, K=1024
// grid = (128 m-tiles, 8 n-tiles): XCD = m-tile % 8 -> A-panel L2 affinity.
template <int MODE>
__global__ __launch_bounds__(256) void gemm_proj(
    const __bf16* __restrict__ A, const __bf16* __restrict__ Bw,
    const float* __restrict__ bias, const float* __restrict__ rel,
    __bf16* __restrict__ obf, float* __restrict__ of32) {
  __shared__ alignas(16) __bf16 As[128 * 64];
  __shared__ alignas(16) __bf16 Bs[128 * 64];
  const int tid = threadIdx.x;
  const int lane = tid & 63;
  const int wave = tid >> 6;
  const int wr = wave >> 1, wc = wave & 1;
  const int lr = lane & 15, lk = (lane >> 4) * 8;
  const int bm = blockIdx.x, bn = blockIdx.y;

  f32x4 acc[4][4];
#pragma unroll
  for (int i = 0; i < 4; ++i)
#pragma unroll
    for (int j = 0; j < 4; ++j)
#pragma unroll
      for (int e = 0; e < 4; ++e) acc[i][j][e] = 0.f;

  const __bf16* Ab = A + (size_t)bm * 128 * 1024;
  const __bf16* Bb = Bw + (size_t)bn * 128 * 1024;
  const int sr = tid >> 3;
  const int sc = (tid & 7) * 8;

  for (int kt = 0; kt < 1024; kt += 64) {
#pragma unroll
    for (int i = 0; i < 4; ++i) {
      gload_lds16(Ab + (size_t)(sr + i * 32) * 1024 + kt + sc, As + tid * 8 + i * 2048);
      gload_lds16(Bb + (size_t)(sr + i * 32) * 1024 + kt + sc, Bs + tid * 8 + i * 2048);
    }
    __syncthreads();
#pragma unroll
    for (int kk = 0; kk < 64; kk += 32) {
      bf8 a[4], b[4];
#pragma unroll
      for (int mi = 0; mi < 4; ++mi)
        a[mi] = *reinterpret_cast<const bf8*>(&As[(wr * 64 + mi * 16 + lr) * 64 + kk + lk]);
#pragma unroll
      for (int ni = 0; ni < 4; ++ni)
        b[ni] = *reinterpret_cast<const bf8*>(&Bs[(wc * 64 + ni * 16 + lr) * 64 + kk + lk]);
#pragma unroll
      for (int mi = 0; mi < 4; ++mi)
#pragma unroll
        for (int ni = 0; ni < 4; ++ni)
          acc[mi][ni] = __builtin_amdgcn_mfma_f32_16x16x32_bf16(a[mi], b[ni], acc[mi][ni], 0, 0, 0);
    }
    __syncthreads();
  }

  const int mBase = bm * 128 + wr * 64;
  const int nBase = bn * 128 + wc * 64;
#pragma unroll
  for (int mi = 0; mi < 4; ++mi) {
#pragma unroll
    for (int ni = 0; ni < 4; ++ni) {
      const int n = nBase + ni * 16 + lr;
#pragma unroll
      for (int r = 0; r < 4; ++r) {
        const int m = mBase + mi * 16 + (lane >> 4) * 4 + r;
        float v = acc[mi][ni][r] + bias[n];
        if (MODE == 0) v *= rel[n];
        if (MODE == 2) {
          of32[(size_t)m * 1024 + n] = v;
        } else if (MODE == 0) {
          size_t idx = ((size_t)((m >> 9) * 8 + (n >> 7))) * 65536 +
                       (size_t)(m & 511) * 128 + (n & 127);
          obf[idx] = (__bf16)v;
        } else {
          size_t idx = ((size_t)((m >> 9) * 8 + (n >> 7))) * 65536 +
                       (size_t)(n & 127) * 512 + (m & 511);
          obf[idx] = (__bf16)v;
        }
      }
    }
  }
}

// ---------------- adj: per-head column softmax, x1e4, CENTERED bf16, TRANSPOSED ----------------
// adjT[h][j][i] = bf16( 10000 * softmax_j((j==i)?0:dot18) - 19.53125 )
// The per-(row of fr) constant cancels in the final softmax; centering keeps
// bf16 ulp ~0.008 (values are ~19.5 +/- few).
__global__ __launch_bounds__(256) void adj_kernel(const float* __restrict__ ch_all,
                                                  const float* __restrict__ ct_all,
                                                  __bf16* __restrict__ adjT) {
  const int wave = threadIdx.x >> 6, lane = threadIdx.x & 63;
  const int row = blockIdx.x * 4 + wave;  // 0..4095
  const int h = row >> 9, i = row & 511;
  float ch[18];
  const float* chp = ch_all + ((size_t)h * 512 + i) * 18;
#pragma unroll
  for (int t = 0; t < 18; ++t) ch[t] = chp[t];
  float e[8];
  float m = -1e30f;
#pragma unroll
  for (int jj = 0; jj < 8; ++jj) {
    const int j = jj * 64 + lane;
    const float* ctp = ct_all + ((size_t)h * 512 + j) * 18;
    float d = 0.f;
#pragma unroll
    for (int t = 0; t < 18; ++t) d += ch[t] * ctp[t];
    if (j == i) d = 0.f;
    e[jj] = d;
    m = fmaxf(m, d);
  }
#pragma unroll
  for (int off = 32; off >= 1; off >>= 1) m = fmaxf(m, __shfl_xor(m, off));
  float s = 0.f;
#pragma unroll
  for (int jj = 0; jj < 8; ++jj) { e[jj] = __expf(e[jj] - m); s += e[jj]; }
#pragma unroll
  for (int off = 32; off >= 1; off >>= 1) s += __shfl_xor(s, off);
  const float inv = 10000.f / s;
  __bf16* op = adjT + (size_t)h * 262144 + i;  // column i of [512][512]
#pragma unroll
  for (int jj = 0; jj < 8; ++jj)
    op[(size_t)(jj * 64 + lane) * 512] = (__bf16)(e[jj] * inv - 19.53125f);
}

// ---------------- fused attention core: scores + row-softmax + PV ----------------
// grid x=b (32), y=h*8+qt (64): XCD = b%8. Same-(h,qt) blocks (sharing the
// 64KB adjT slice) are ADJACENT in per-XCD dispatch order -> L2-hot reuse;
// same-bh qt-blocks still co-XCD (ft/fv reuse, window of 4 ids).
__global__ __launch_bounds__(256, 3) void fused_attn_kernel(
    const __bf16* __restrict__ fh, const __bf16* __restrict__ ft,
    const __bf16* __restrict__ fvT, const __bf16* __restrict__ adjT,
    float* __restrict__ fr, __bf16* __restrict__ ctx) {
  __shared__ alignas(16) __bf16 Bt[128 * 128];    // 32 KB staging (ft / fv tiles)
  __shared__ alignas(16) __bf16 Pl[4][16 * 128];  // 16 KB, per-wave P chunk
  const int tid = threadIdx.x;
  const int l = tid & 63, w = tid >> 6;
  const int b = blockIdx.x;            // 0..31 -> XCD = b&7
  const int h = blockIdx.y >> 3;       // 0..7
  const int qt = blockIdx.y & 7;       // 0..7
  const int bh = b * 8 + h;
  const int wrow = qt * 64 + w * 16;
  const int lr = l & 15;
  const int khi = l >> 4;  // 0..3

  // staging source pre-swizzle: LDS[row][cc] <- G[row][cc ^ (row&7)]
  const int srow = tid >> 4;                 // row within 16-row group
  const int scc = (tid & 15) ^ (srow & 7);   // source chunk

  // A fragments for QK^T: wave's own 16 rows of fh
  bf8 afr[4];
  {
    const __bf16* ap = fh + (size_t)bh * 65536 + (size_t)(wrow + lr) * 128 + khi * 8;
#pragma unroll
    for (int kk4 = 0; kk4 < 4; ++kk4)
      afr[kk4] = *reinterpret_cast<const bf8*>(ap + kk4 * 32);
  }

  f32x4 acc[32];
#pragma unroll
  for (int n = 0; n < 32; ++n)
#pragma unroll
    for (int e = 0; e < 4; ++e) acc[n][e] = 0.f;

  // ---- phase 1: S = fh . ft^T ----
  const __bf16* ftb = ft + (size_t)bh * 65536;
#pragma unroll
  for (int kt = 0; kt < 4; ++kt) {
#pragma unroll
    for (int i = 0; i < 8; ++i)
      gload_lds16(ftb + (size_t)(kt * 128 + i * 16 + srow) * 128 + scc * 8,
                  Bt + i * 2048 + tid * 8);
    __syncthreads();
    __builtin_amdgcn_s_setprio(1);
#pragma unroll
    for (int kk4 = 0; kk4 < 4; ++kk4) {
      bf8 bfr[8];
#pragma unroll
      for (int n2 = 0; n2 < 8; ++n2)
        bfr[n2] = *reinterpret_cast<const bf8*>(
            &Bt[(n2 * 16 + lr) * 128 + ((kk4 * 4 + khi) ^ (lr & 7)) * 8]);
#pragma unroll
      for (int n2 = 0; n2 < 8; ++n2)
        acc[kt * 8 + n2] =
            __builtin_amdgcn_mfma_f32_16x16x32_bf16(afr[kk4], bfr[n2], acc[kt * 8 + n2], 0, 0, 0);
    }
    __builtin_amdgcn_s_setprio(0);
    __syncthreads();
  }

  // ---- phase 2: logits = S/sqrt(128) + adjT(centered); in-register row softmax ----
  const float scale = 0.08838834764831845f;  // 1/sqrt(128)
  const __bf16* adjTp = adjT + (size_t)h * 262144;
  float mrow[4] = {-1e30f, -1e30f, -1e30f, -1e30f};
#pragma unroll
  for (int n = 0; n < 32; ++n) {
    const int col = n * 16 + lr;
    bf4 av4 = *reinterpret_cast<const bf4*>(adjTp + (size_t)col * 512 + wrow + khi * 4);
#pragma unroll
    for (int r = 0; r < 4; ++r) {
      float v = acc[n][r] * scale + (float)av4[r];
      acc[n][r] = v;
      mrow[r] = fmaxf(mrow[r], v);
    }
  }
#pragma unroll
  for (int r = 0; r < 4; ++r)
#pragma unroll
    for (int off = 1; off <= 8; off <<= 1) mrow[r] = fmaxf(mrow[r], __shfl_xor(mrow[r], off));
  float srw[4] = {0.f, 0.f, 0.f, 0.f};
#pragma unroll
  for (int n = 0; n < 32; ++n)
#pragma unroll
    for (int r = 0; r < 4; ++r) {
      float e = __expf(acc[n][r] - mrow[r]);
      acc[n][r] = e;
      srw[r] += e;
    }
#pragma unroll
  for (int r = 0; r < 4; ++r)
#pragma unroll
    for (int off = 1; off <= 8; off <<= 1) srw[r] += __shfl_xor(srw[r], off);
  float inv[4];
#pragma unroll
  for (int r = 0; r < 4; ++r) inv[r] = 1.f / srw[r];
#pragma unroll
  for (int n = 0; n < 32; ++n)
#pragma unroll
    for (int r = 0; r < 4; ++r) acc[n][r] *= inv[r];

  // prefetch fv tile 0 (Bt free: last QK barrier passed); overlaps fr writes
  const __bf16* fvb = fvT + (size_t)bh * 65536;
#pragma unroll
  for (int i = 0; i < 8; ++i)
    gload_lds16(fvb + (size_t)(i * 16 + srow) * 512 + scc * 8, Bt + i * 2048 + tid * 8);

  // write fr (required output), once
  {
    float* frb = fr + (size_t)bh * 262144;
#pragma unroll
    for (int n = 0; n < 32; ++n) {
      const int col = n * 16 + lr;
#pragma unroll
      for (int r = 0; r < 4; ++r)
        frb[(size_t)(wrow + khi * 4 + r) * 512 + col] = acc[n][r];
    }
  }

  // ---- phase 3: PV via per-wave LDS bounce of P chunks ----
  f32x4 acc2[8];
#pragma unroll
  for (int n2 = 0; n2 < 8; ++n2)
#pragma unroll
    for (int e = 0; e < 4; ++e) acc2[n2][e] = 0.f;

  __bf16* Pw = &Pl[w][0];
#pragma unroll
  for (int kt = 0; kt < 4; ++kt) {
    // bounce own P chunk kt into swizzled per-wave LDS (C-layout -> A-frag layout)
#pragma unroll
    for (int n2 = 0; n2 < 8; ++n2) {
      const int colc = n2 * 2 + (lr >> 3);  // logical chunk = col>>3
      const int cl = lr & 7;
#pragma unroll
      for (int r = 0; r < 4; ++r) {
        const int q = khi * 4 + r;
        Pw[q * 128 + ((colc ^ (q & 7)) * 8) + cl] = (__bf16)acc[kt * 8 + n2][r];
      }
    }
    __syncthreads();  // fv(kt) staged (vmcnt) + P writes done (lgkm)
    __builtin_amdgcn_s_setprio(1);
#pragma unroll
    for (int kk4 = 0; kk4 < 4; ++kk4) {
      bf8 pa = *reinterpret_cast<const bf8*>(
          &Pw[lr * 128 + ((kk4 * 4 + khi) ^ (lr & 7)) * 8]);
      bf8 bfr[8];
#pragma unroll
      for (int n2 = 0; n2 < 8; ++n2)
        bfr[n2] = *reinterpret_cast<const bf8*>(
            &Bt[(n2 * 16 + lr) * 128 + ((kk4 * 4 + khi) ^ (lr & 7)) * 8]);
#pragma unroll
      for (int n2 = 0; n2 < 8; ++n2)
        acc2[n2] = __builtin_amdgcn_mfma_f32_16x16x32_bf16(pa, bfr[n2], acc2[n2], 0, 0, 0);
    }
    __builtin_amdgcn_s_setprio(0);
    __syncthreads();  // all reads of Bt(kt) done
    if (kt < 3) {
      const int ktn = kt + 1;
#pragma unroll
      for (int i = 0; i < 8; ++i)
        gload_lds16(fvb + (size_t)(i * 16 + srow) * 512 + ktn * 128 + scc * 8,
                    Bt + i * 2048 + tid * 8);
    }
  }

#pragma unroll
  for (int n2 = 0; n2 < 8; ++n2) {
    const int c = n2 * 16 + lr;
#pragma unroll
    for (int r = 0; r < 4; ++r) {
      const int q = wrow + khi * 4 + r;
      ctx[(size_t)(b * 512 + q) * 1024 + h * 128 + c] = (__bf16)acc2[n2][r];
    }
  }
}

extern "C" void kernel_launch(void* const* d_in, const int* in_sizes, int n_in,
                              void* d_out, int out_size, void* d_ws, size_t ws_size,
                              hipStream_t stream) {
  const float* x_q  = (const float*)d_in[0];
  const float* x_kv = (const float*)d_in[1];
  const float* Wh   = (const float*)d_in[2];
  const float* bh   = (const float*)d_in[3];
  const float* Wv   = (const float*)d_in[4];
  const float* bv   = (const float*)d_in[5];
  const float* Wo   = (const float*)d_in[6];
  const float* bo   = (const float*)d_in[7];
  const float* rel  = (const float*)d_in[8];
  const float* colh = (const float*)d_in[9];
  const float* colt = (const float*)d_in[10];

  float* out = (float*)d_out;
  float* fr  = out + 16777216;  // 32*512*1024 floats, then 256*512*512 floats

  __bf16* xq_bf  = (__bf16*)d_ws;
  __bf16* xkv_bf = xq_bf + 16777216;
  __bf16* Wh_bf  = xkv_bf + 16777216;
  __bf16* Wv_bf  = Wh_bf + 1048576;
  __bf16* Wo_bf  = Wv_bf + 1048576;
  __bf16* fhead  = Wo_bf + 1048576;
  __bf16* ftail  = fhead + 16777216;
  __bf16* fvT    = ftail + 16777216;
  __bf16* adjT   = fvT + 16777216;
  __bf16* ctx    = adjT + 2097152;

  cvt_kernel<<<4096, 256, 0, stream>>>(x_q, xq_bf, 4194304);
  cvt_kernel<<<4096, 256, 0, stream>>>(x_kv, xkv_bf, 4194304);
  cvt_kernel<<<1024, 256, 0, stream>>>(Wh, Wh_bf, 262144);
  cvt_kernel<<<1024, 256, 0, stream>>>(Wv, Wv_bf, 262144);
  cvt_kernel<<<1024, 256, 0, stream>>>(Wo, Wo_bf, 262144);

  dim3 gp(128, 8);
  gemm_proj<0><<<gp, 256, 0, stream>>>(xq_bf, Wh_bf, bh, rel, fhead, nullptr);
  gemm_proj<0><<<gp, 256, 0, stream>>>(xkv_bf, Wh_bf, bh, rel, ftail, nullptr);
  gemm_proj<1><<<gp, 256, 0, stream>>>(xkv_bf, Wv_bf, bv, nullptr, fvT, nullptr);

  adj_kernel<<<1024, 256, 0, stream>>>(colh, colt, adjT);

  fused_attn_kernel<<<dim3(32, 64), 256, 0, stream>>>(fhead, ftail, fvT, adjT, fr, ctx);

  gemm_proj<2><<<gp, 256, 0, stream>>>(ctx, Wo_bf, bo, nullptr, nullptr, out);
}

// Round 9
// 817.123 us; speedup vs baseline: 1.1431x; 1.0747x over previous
//
#include <hip/hip_runtime.h>

typedef __attribute__((ext_vector_type(8))) __bf16 bf8;
typedef __attribute__((ext_vector_type(4))) __bf16 bf4;
typedef __attribute__((ext_vector_type(4))) float f32x4;

#define DEVI static __device__ __forceinline__

// async global->LDS, 16B per lane. LDS dest must be linear in lane order.
DEVI void gload_lds16(const void* g, void* l) {
  __builtin_amdgcn_global_load_lds(
      (const __attribute__((address_space(1))) unsigned int*)g,
      (__attribute__((address_space(3))) unsigned int*)l, 16, 0, 0);
}

// counted vmcnt + hard scheduling fence (rule #18: compiler may hoist past asm waits)
#define WAITV(N)                                             \
  asm volatile("s_waitcnt vmcnt(" #N ")" ::: "memory");      \
  __builtin_amdgcn_sched_barrier(0)
#define BARRIER()                      \
  __builtin_amdgcn_sched_barrier(0);   \
  __builtin_amdgcn_s_barrier();        \
  __builtin_amdgcn_sched_barrier(0)

// ---------------- f32 -> bf16 convert ----------------
__global__ __launch_bounds__(256) void cvt_kernel(const float* __restrict__ in,
                                                  __bf16* __restrict__ out, int n4) {
  int stride = gridDim.x * blockDim.x;
  for (int i = blockIdx.x * blockDim.x + threadIdx.x; i < n4; i += stride) {
    f32x4 v = reinterpret_cast<const f32x4*>(in)[i];
    bf4 o;
    o[0] = (__bf16)v[0]; o[1] = (__bf16)v[1]; o[2] = (__bf16)v[2]; o[3] = (__bf16)v[3];
    reinterpret_cast<bf4*>(out)[i] = o;
  }
}

// ---------------- projection GEMM: 256x256 tile, 8 waves, 2-deep counted-vmcnt pipeline ----
// C[m][n] = sum_k A[m][k] * Bw[n][k] (+bias[n]); M=16384, N=1024, K=1024.
// grid (64 bm, 4 bn): XCD = bm%8; the 4 bn-blocks of each bm are co-XCD (ids
// bm, bm+64, ... stride 64 == 0 mod 8) -> A-panel read once from HBM per XCD.
// LDS 128KB = 2 dbuf x (A 32KB + B 32KB). STAGE(t+2) issued after the
// buffer-release barrier; steady-state wait is vmcnt(8) (the other buffer's
// loads stay in flight across barriers - T3/T4). XOR-chunk swizzle on stage
// source + ds_read (rule #21 both-sides involution; 2-way bank alias = free).
template <int MODE>
__global__ __launch_bounds__(512, 2) void gemm_proj(
    const __bf16* __restrict__ A, const __bf16* __restrict__ Bw,
    const float* __restrict__ bias, const float* __restrict__ rel,
    __bf16* __restrict__ obf, float* __restrict__ of32) {
  __shared__ alignas(16) __bf16 As0[256 * 64];
  __shared__ alignas(16) __bf16 Bs0[256 * 64];
  __shared__ alignas(16) __bf16 As1[256 * 64];
  __shared__ alignas(16) __bf16 Bs1[256 * 64];
  const int tid = threadIdx.x;
  const int lane = tid & 63;
  const int wave = tid >> 6;           // 0..7
  const int wr = wave >> 2;            // 0..1  (M split)
  const int wc = wave & 3;             // 0..3  (N split)
  const int lr = lane & 15;
  const int khi = lane >> 4;           // 0..3
  const int bm = blockIdx.x, bn = blockIdx.y;

  const __bf16* Ab = A + (size_t)bm * 256 * 1024;
  const __bf16* Bb = Bw + (size_t)bn * 256 * 1024;

  // staging: round i covers rows i*64+(tid>>3), chunk tid&7 (8 bf16 chunks/row).
  // source chunk pre-swizzled by row&7 so linear LDS + swizzled read match.
  const int srow = tid >> 3;                // 0..63, row&7 == srow&7 for all i
  const int scc = (tid & 7) ^ (srow & 7);   // pre-swizzled source chunk

  f32x4 acc[8][4];
#pragma unroll
  for (int mi = 0; mi < 8; ++mi)
#pragma unroll
    for (int ni = 0; ni < 4; ++ni)
#pragma unroll
      for (int e = 0; e < 4; ++e) acc[mi][ni][e] = 0.f;

  auto STAGE = [&](const __bf16* gb, __bf16* lds, int kt) {
#pragma unroll
    for (int i = 0; i < 4; ++i)
      gload_lds16(gb + (size_t)(i * 64 + srow) * 1024 + kt * 64 + scc * 8,
                  lds + i * 4096 + tid * 8);
  };

  auto COMPUTE = [&](const __bf16* As, const __bf16* Bs) {
    __builtin_amdgcn_s_setprio(1);
#pragma unroll
    for (int kk = 0; kk < 2; ++kk) {
      const int ck = ((kk * 4 + khi) ^ (lr & 7)) * 8;
      bf8 a[8], b[4];
#pragma unroll
      for (int mi = 0; mi < 8; ++mi)
        a[mi] = *reinterpret_cast<const bf8*>(&As[(wr * 128 + mi * 16 + lr) * 64 + ck]);
#pragma unroll
      for (int ni = 0; ni < 4; ++ni)
        b[ni] = *reinterpret_cast<const bf8*>(&Bs[(wc * 64 + ni * 16 + lr) * 64 + ck]);
#pragma unroll
      for (int mi = 0; mi < 8; ++mi)
#pragma unroll
        for (int ni = 0; ni < 4; ++ni)
          acc[mi][ni] = __builtin_amdgcn_mfma_f32_16x16x32_bf16(a[mi], b[ni], acc[mi][ni], 0, 0, 0);
    }
    __builtin_amdgcn_s_setprio(0);
  };

  // prologue: two tiles in flight (16 loads)
  STAGE(Ab, As0, 0); STAGE(Bb, Bs0, 0);
  STAGE(Ab, As1, 1); STAGE(Bb, Bs1, 1);

  for (int it = 0; it < 7; ++it) {
    WAITV(8);            // buf0's 8 loads landed (buf1's 8 still in flight)
    BARRIER();
    COMPUTE(As0, Bs0);
    BARRIER();           // all waves done reading buf0
    STAGE(Ab, As0, 2 * it + 2); STAGE(Bb, Bs0, 2 * it + 2);
    WAITV(8);
    BARRIER();
    COMPUTE(As1, Bs1);
    BARRIER();
    STAGE(Ab, As1, 2 * it + 3); STAGE(Bb, Bs1, 2 * it + 3);
  }
  // tail: tiles 14 (buf0) and 15 (buf1), no more staging
  WAITV(8);
  BARRIER();
  COMPUTE(As0, Bs0);
  WAITV(0);
  BARRIER();
  COMPUTE(As1, Bs1);

  // epilogue
#pragma unroll
  for (int mi = 0; mi < 8; ++mi) {
#pragma unroll
    for (int ni = 0; ni < 4; ++ni) {
      const int n = bn * 256 + wc * 64 + ni * 16 + lr;
#pragma unroll
      for (int r = 0; r < 4; ++r) {
        const int m = bm * 256 + wr * 128 + mi * 16 + khi * 4 + r;
        float v = acc[mi][ni][r] + bias[n];
        if (MODE == 0) v *= rel[n];
        if (MODE == 2) {
          of32[(size_t)m * 1024 + n] = v;
        } else if (MODE == 0) {
          size_t idx = ((size_t)((m >> 9) * 8 + (n >> 7))) * 65536 +
                       (size_t)(m & 511) * 128 + (n & 127);
          obf[idx] = (__bf16)v;
        } else {
          size_t idx = ((size_t)((m >> 9) * 8 + (n >> 7))) * 65536 +
                       (size_t)(n & 127) * 512 + (m & 511);
          obf[idx] = (__bf16)v;
        }
      }
    }
  }
}

// ---------------- adj: per-head column softmax, x1e4, CENTERED bf16, TRANSPOSED ----------------
// adjT[h][j][i] = bf16( 10000 * softmax_j((j==i)?0:dot18) - 19.53125 )
__global__ __launch_bounds__(256) void adj_kernel(const float* __restrict__ ch_all,
                                                  const float* __restrict__ ct_all,
                                                  __bf16* __restrict__ adjT) {
  const int wave = threadIdx.x >> 6, lane = threadIdx.x & 63;
  const int row = blockIdx.x * 4 + wave;  // 0..4095
  const int h = row >> 9, i = row & 511;
  float ch[18];
  const float* chp = ch_all + ((size_t)h * 512 + i) * 18;
#pragma unroll
  for (int t = 0; t < 18; ++t) ch[t] = chp[t];
  float e[8];
  float m = -1e30f;
#pragma unroll
  for (int jj = 0; jj < 8; ++jj) {
    const int j = jj * 64 + lane;
    const float* ctp = ct_all + ((size_t)h * 512 + j) * 18;
    float d = 0.f;
#pragma unroll
    for (int t = 0; t < 18; ++t) d += ch[t] * ctp[t];
    if (j == i) d = 0.f;
    e[jj] = d;
    m = fmaxf(m, d);
  }
#pragma unroll
  for (int off = 32; off >= 1; off >>= 1) m = fmaxf(m, __shfl_xor(m, off));
  float s = 0.f;
#pragma unroll
  for (int jj = 0; jj < 8; ++jj) { e[jj] = __expf(e[jj] - m); s += e[jj]; }
#pragma unroll
  for (int off = 32; off >= 1; off >>= 1) s += __shfl_xor(s, off);
  const float inv = 10000.f / s;
  __bf16* op = adjT + (size_t)h * 262144 + i;  // column i of [512][512]
#pragma unroll
  for (int jj = 0; jj < 8; ++jj)
    op[(size_t)(jj * 64 + lane) * 512] = (__bf16)(e[jj] * inv - 19.53125f);
}

// ---------------- fused attention core: scores + row-softmax + PV ----------------
// (unchanged from round 7: 223 us, FETCH 160MB; grid x=b, y=h*8+qt)
__global__ __launch_bounds__(256, 3) void fused_attn_kernel(
    const __bf16* __restrict__ fh, const __bf16* __restrict__ ft,
    const __bf16* __restrict__ fvT, const __bf16* __restrict__ adjT,
    float* __restrict__ fr, __bf16* __restrict__ ctx) {
  __shared__ alignas(16) __bf16 Bt[128 * 128];    // 32 KB staging (ft / fv tiles)
  __shared__ alignas(16) __bf16 Pl[4][16 * 128];  // 16 KB, per-wave P chunk
  const int tid = threadIdx.x;
  const int l = tid & 63, w = tid >> 6;
  const int b = blockIdx.x;            // 0..31 -> XCD = b&7
  const int h = blockIdx.y >> 3;       // 0..7
  const int qt = blockIdx.y & 7;       // 0..7
  const int bh = b * 8 + h;
  const int wrow = qt * 64 + w * 16;
  const int lr = l & 15;
  const int khi = l >> 4;  // 0..3

  const int srow = tid >> 4;                 // row within 16-row group
  const int scc = (tid & 15) ^ (srow & 7);   // source chunk

  bf8 afr[4];
  {
    const __bf16* ap = fh + (size_t)bh * 65536 + (size_t)(wrow + lr) * 128 + khi * 8;
#pragma unroll
    for (int kk4 = 0; kk4 < 4; ++kk4)
      afr[kk4] = *reinterpret_cast<const bf8*>(ap + kk4 * 32);
  }

  f32x4 acc[32];
#pragma unroll
  for (int n = 0; n < 32; ++n)
#pragma unroll
    for (int e = 0; e < 4; ++e) acc[n][e] = 0.f;

  // ---- phase 1: S = fh . ft^T ----
  const __bf16* ftb = ft + (size_t)bh * 65536;
#pragma unroll
  for (int kt = 0; kt < 4; ++kt) {
#pragma unroll
    for (int i = 0; i < 8; ++i)
      gload_lds16(ftb + (size_t)(kt * 128 + i * 16 + srow) * 128 + scc * 8,
                  Bt + i * 2048 + tid * 8);
    __syncthreads();
    __builtin_amdgcn_s_setprio(1);
#pragma unroll
    for (int kk4 = 0; kk4 < 4; ++kk4) {
      bf8 bfr[8];
#pragma unroll
      for (int n2 = 0; n2 < 8; ++n2)
        bfr[n2] = *reinterpret_cast<const bf8*>(
            &Bt[(n2 * 16 + lr) * 128 + ((kk4 * 4 + khi) ^ (lr & 7)) * 8]);
#pragma unroll
      for (int n2 = 0; n2 < 8; ++n2)
        acc[kt * 8 + n2] =
            __builtin_amdgcn_mfma_f32_16x16x32_bf16(afr[kk4], bfr[n2], acc[kt * 8 + n2], 0, 0, 0);
    }
    __builtin_amdgcn_s_setprio(0);
    __syncthreads();
  }

  // ---- phase 2: logits + in-register row softmax ----
  const float scale = 0.08838834764831845f;  // 1/sqrt(128)
  const __bf16* adjTp = adjT + (size_t)h * 262144;
  float mrow[4] = {-1e30f, -1e30f, -1e30f, -1e30f};
#pragma unroll
  for (int n = 0; n < 32; ++n) {
    const int col = n * 16 + lr;
    bf4 av4 = *reinterpret_cast<const bf4*>(adjTp + (size_t)col * 512 + wrow + khi * 4);
#pragma unroll
    for (int r = 0; r < 4; ++r) {
      float v = acc[n][r] * scale + (float)av4[r];
      acc[n][r] = v;
      mrow[r] = fmaxf(mrow[r], v);
    }
  }
#pragma unroll
  for (int r = 0; r < 4; ++r)
#pragma unroll
    for (int off = 1; off <= 8; off <<= 1) mrow[r] = fmaxf(mrow[r], __shfl_xor(mrow[r], off));
  float srw[4] = {0.f, 0.f, 0.f, 0.f};
#pragma unroll
  for (int n = 0; n < 32; ++n)
#pragma unroll
    for (int r = 0; r < 4; ++r) {
      float e = __expf(acc[n][r] - mrow[r]);
      acc[n][r] = e;
      srw[r] += e;
    }
#pragma unroll
  for (int r = 0; r < 4; ++r)
#pragma unroll
    for (int off = 1; off <= 8; off <<= 1) srw[r] += __shfl_xor(srw[r], off);
  float inv[4];
#pragma unroll
  for (int r = 0; r < 4; ++r) inv[r] = 1.f / srw[r];
#pragma unroll
  for (int n = 0; n < 32; ++n)
#pragma unroll
    for (int r = 0; r < 4; ++r) acc[n][r] *= inv[r];

  // prefetch fv tile 0; overlaps fr writes
  const __bf16* fvb = fvT + (size_t)bh * 65536;
#pragma unroll
  for (int i = 0; i < 8; ++i)
    gload_lds16(fvb + (size_t)(i * 16 + srow) * 512 + scc * 8, Bt + i * 2048 + tid * 8);

  // write fr (required output), once
  {
    float* frb = fr + (size_t)bh * 262144;
#pragma unroll
    for (int n = 0; n < 32; ++n) {
      const int col = n * 16 + lr;
#pragma unroll
      for (int r = 0; r < 4; ++r)
        frb[(size_t)(wrow + khi * 4 + r) * 512 + col] = acc[n][r];
    }
  }

  // ---- phase 3: PV via per-wave LDS bounce of P chunks ----
  f32x4 acc2[8];
#pragma unroll
  for (int n2 = 0; n2 < 8; ++n2)
#pragma unroll
    for (int e = 0; e < 4; ++e) acc2[n2][e] = 0.f;

  __bf16* Pw = &Pl[w][0];
#pragma unroll
  for (int kt = 0; kt < 4; ++kt) {
#pragma unroll
    for (int n2 = 0; n2 < 8; ++n2) {
      const int colc = n2 * 2 + (lr >> 3);
      const int cl = lr & 7;
#pragma unroll
      for (int r = 0; r < 4; ++r) {
        const int q = khi * 4 + r;
        Pw[q * 128 + ((colc ^ (q & 7)) * 8) + cl] = (__bf16)acc[kt * 8 + n2][r];
      }
    }
    __syncthreads();  // fv(kt) staged (vmcnt) + P writes done (lgkm)
    __builtin_amdgcn_s_setprio(1);
#pragma unroll
    for (int kk4 = 0; kk4 < 4; ++kk4) {
      bf8 pa = *reinterpret_cast<const bf8*>(
          &Pw[lr * 128 + ((kk4 * 4 + khi) ^ (lr & 7)) * 8]);
      bf8 bfr[8];
#pragma unroll
      for (int n2 = 0; n2 < 8; ++n2)
        bfr[n2] = *reinterpret_cast<const bf8*>(
            &Bt[(n2 * 16 + lr) * 128 + ((kk4 * 4 + khi) ^ (lr & 7)) * 8]);
#pragma unroll
      for (int n2 = 0; n2 < 8; ++n2)
        acc2[n2] = __builtin_amdgcn_mfma_f32_16x16x32_bf16(pa, bfr[n2], acc2[n2], 0, 0, 0);
    }
    __builtin_amdgcn_s_setprio(0);
    __syncthreads();
    if (kt < 3) {
      const int ktn = kt + 1;
#pragma unroll
      for (int i = 0; i < 8; ++i)
        gload_lds16(fvb + (size_t)(i * 16 + srow) * 512 + ktn * 128 + scc * 8,
                    Bt + i * 2048 + tid * 8);
    }
  }

#pragma unroll
  for (int n2 = 0; n2 < 8; ++n2) {
    const int c = n2 * 16 + lr;
#pragma unroll
    for (int r = 0; r < 4; ++r) {
      const int q = wrow + khi * 4 + r;
      ctx[(size_t)(b * 512 + q) * 1024 + h * 128 + c] = (__bf16)acc2[n2][r];
    }
  }
}

extern "C" void kernel_launch(void* const* d_in, const int* in_sizes, int n_in,
                              void* d_out, int out_size, void* d_ws, size_t ws_size,
                              hipStream_t stream) {
  const float* x_q  = (const float*)d_in[0];
  const float* x_kv = (const float*)d_in[1];
  const float* Wh   = (const float*)d_in[2];
  const float* bh   = (const float*)d_in[3];
  const float* Wv   = (const float*)d_in[4];
  const float* bv   = (const float*)d_in[5];
  const float* Wo   = (const float*)d_in[6];
  const float* bo   = (const float*)d_in[7];
  const float* rel  = (const float*)d_in[8];
  const float* colh = (const float*)d_in[9];
  const float* colt = (const float*)d_in[10];

  float* out = (float*)d_out;
  float* fr  = out + 16777216;  // 32*512*1024 floats, then 256*512*512 floats

  __bf16* xq_bf  = (__bf16*)d_ws;
  __bf16* xkv_bf = xq_bf + 16777216;
  __bf16* Wh_bf  = xkv_bf + 16777216;
  __bf16* Wv_bf  = Wh_bf + 1048576;
  __bf16* Wo_bf  = Wv_bf + 1048576;
  __bf16* fhead  = Wo_bf + 1048576;
  __bf16* ftail  = fhead + 16777216;
  __bf16* fvT    = ftail + 16777216;
  __bf16* adjT   = fvT + 16777216;
  __bf16* ctx    = adjT + 2097152;

  cvt_kernel<<<4096, 256, 0, stream>>>(x_q, xq_bf, 4194304);
  cvt_kernel<<<4096, 256, 0, stream>>>(x_kv, xkv_bf, 4194304);
  cvt_kernel<<<1024, 256, 0, stream>>>(Wh, Wh_bf, 262144);
  cvt_kernel<<<1024, 256, 0, stream>>>(Wv, Wv_bf, 262144);
  cvt_kernel<<<1024, 256, 0, stream>>>(Wo, Wo_bf, 262144);

  dim3 gp(64, 4);
  gemm_proj<0><<<gp, 512, 0, stream>>>(xq_bf, Wh_bf, bh, rel, fhead, nullptr);
  gemm_proj<0><<<gp, 512, 0, stream>>>(xkv_bf, Wh_bf, bh, rel, ftail, nullptr);
  gemm_proj<1><<<gp, 512, 0, stream>>>(xkv_bf, Wv_bf, bv, nullptr, fvT, nullptr);

  adj_kernel<<<1024, 256, 0, stream>>>(colh, colt, adjT);

  fused_attn_kernel<<<dim3(32, 64), 256, 0, stream>>>(fhead, ftail, fvT, adjT, fr, ctx);

  gemm_proj<2><<<gp, 512, 0, stream>>>(ctx, Wo_bf, bo, nullptr, nullptr, out);
}

// Round 10
// 726.818 us; speedup vs baseline: 1.2851x; 1.1242x over previous
//
#include <hip/hip_runtime.h>

typedef __attribute__((ext_vector_type(8))) __bf16 bf8;
typedef __attribute__((ext_vector_type(4))) __bf16 bf4;
typedef __attribute__((ext_vector_type(4))) float f32x4;

#define DEVI static __device__ __forceinline__

// async global->LDS, 16B per lane. LDS dest must be linear in lane order.
DEVI void gload_lds16(const void* g, void* l) {
  __builtin_amdgcn_global_load_lds(
      (const __attribute__((address_space(1))) unsigned int*)g,
      (__attribute__((address_space(3))) unsigned int*)l, 16, 0, 0);
}

// counted vmcnt + hard scheduling fence (rule #18: compiler may hoist past asm waits)
#define WAITV(N)                                             \
  asm volatile("s_waitcnt vmcnt(" #N ")" ::: "memory");      \
  __builtin_amdgcn_sched_barrier(0)
#define LGKM0()                                              \
  asm volatile("s_waitcnt lgkmcnt(0)" ::: "memory");         \
  __builtin_amdgcn_sched_barrier(0)
#define BARRIER()                      \
  __builtin_amdgcn_sched_barrier(0);   \
  __builtin_amdgcn_s_barrier();        \
  __builtin_amdgcn_sched_barrier(0)

// ---------------- f32 -> bf16 convert ----------------
__global__ __launch_bounds__(256) void cvt_kernel(const float* __restrict__ in,
                                                  __bf16* __restrict__ out, int n4) {
  int stride = gridDim.x * blockDim.x;
  for (int i = blockIdx.x * blockDim.x + threadIdx.x; i < n4; i += stride) {
    f32x4 v = reinterpret_cast<const f32x4*>(in)[i];
    bf4 o;
    o[0] = (__bf16)v[0]; o[1] = (__bf16)v[1]; o[2] = (__bf16)v[2]; o[3] = (__bf16)v[3];
    reinterpret_cast<bf4*>(out)[i] = o;
  }
}

// ---------------- projection GEMM: 256x256 tile, 8 waves, 2-deep counted-vmcnt pipeline ----
// (unchanged from round 9 — measured working, ~570 TF)
template <int MODE>
__global__ __launch_bounds__(512, 2) void gemm_proj(
    const __bf16* __restrict__ A, const __bf16* __restrict__ Bw,
    const float* __restrict__ bias, const float* __restrict__ rel,
    __bf16* __restrict__ obf, float* __restrict__ of32) {
  __shared__ alignas(16) __bf16 As0[256 * 64];
  __shared__ alignas(16) __bf16 Bs0[256 * 64];
  __shared__ alignas(16) __bf16 As1[256 * 64];
  __shared__ alignas(16) __bf16 Bs1[256 * 64];
  const int tid = threadIdx.x;
  const int lane = tid & 63;
  const int wave = tid >> 6;           // 0..7
  const int wr = wave >> 2;            // 0..1  (M split)
  const int wc = wave & 3;             // 0..3  (N split)
  const int lr = lane & 15;
  const int khi = lane >> 4;           // 0..3
  const int bm = blockIdx.x, bn = blockIdx.y;

  const __bf16* Ab = A + (size_t)bm * 256 * 1024;
  const __bf16* Bb = Bw + (size_t)bn * 256 * 1024;

  const int srow = tid >> 3;                // 0..63, row&7 == srow&7 for all i
  const int scc = (tid & 7) ^ (srow & 7);   // pre-swizzled source chunk

  f32x4 acc[8][4];
#pragma unroll
  for (int mi = 0; mi < 8; ++mi)
#pragma unroll
    for (int ni = 0; ni < 4; ++ni)
#pragma unroll
      for (int e = 0; e < 4; ++e) acc[mi][ni][e] = 0.f;

  auto STAGE = [&](const __bf16* gb, __bf16* lds, int kt) {
#pragma unroll
    for (int i = 0; i < 4; ++i)
      gload_lds16(gb + (size_t)(i * 64 + srow) * 1024 + kt * 64 + scc * 8,
                  lds + i * 4096 + tid * 8);
  };

  auto COMPUTE = [&](const __bf16* As, const __bf16* Bs) {
    __builtin_amdgcn_s_setprio(1);
#pragma unroll
    for (int kk = 0; kk < 2; ++kk) {
      const int ck = ((kk * 4 + khi) ^ (lr & 7)) * 8;
      bf8 a[8], b[4];
#pragma unroll
      for (int mi = 0; mi < 8; ++mi)
        a[mi] = *reinterpret_cast<const bf8*>(&As[(wr * 128 + mi * 16 + lr) * 64 + ck]);
#pragma unroll
      for (int ni = 0; ni < 4; ++ni)
        b[ni] = *reinterpret_cast<const bf8*>(&Bs[(wc * 64 + ni * 16 + lr) * 64 + ck]);
#pragma unroll
      for (int mi = 0; mi < 8; ++mi)
#pragma unroll
        for (int ni = 0; ni < 4; ++ni)
          acc[mi][ni] = __builtin_amdgcn_mfma_f32_16x16x32_bf16(a[mi], b[ni], acc[mi][ni], 0, 0, 0);
    }
    __builtin_amdgcn_s_setprio(0);
  };

  STAGE(Ab, As0, 0); STAGE(Bb, Bs0, 0);
  STAGE(Ab, As1, 1); STAGE(Bb, Bs1, 1);

  for (int it = 0; it < 7; ++it) {
    WAITV(8);
    BARRIER();
    COMPUTE(As0, Bs0);
    BARRIER();
    STAGE(Ab, As0, 2 * it + 2); STAGE(Bb, Bs0, 2 * it + 2);
    WAITV(8);
    BARRIER();
    COMPUTE(As1, Bs1);
    BARRIER();
    STAGE(Ab, As1, 2 * it + 3); STAGE(Bb, Bs1, 2 * it + 3);
  }
  WAITV(8);
  BARRIER();
  COMPUTE(As0, Bs0);
  WAITV(0);
  BARRIER();
  COMPUTE(As1, Bs1);

#pragma unroll
  for (int mi = 0; mi < 8; ++mi) {
#pragma unroll
    for (int ni = 0; ni < 4; ++ni) {
      const int n = bn * 256 + wc * 64 + ni * 16 + lr;
#pragma unroll
      for (int r = 0; r < 4; ++r) {
        const int m = bm * 256 + wr * 128 + mi * 16 + khi * 4 + r;
        float v = acc[mi][ni][r] + bias[n];
        if (MODE == 0) v *= rel[n];
        if (MODE == 2) {
          of32[(size_t)m * 1024 + n] = v;
        } else if (MODE == 0) {
          size_t idx = ((size_t)((m >> 9) * 8 + (n >> 7))) * 65536 +
                       (size_t)(m & 511) * 128 + (n & 127);
          obf[idx] = (__bf16)v;
        } else {
          size_t idx = ((size_t)((m >> 9) * 8 + (n >> 7))) * 65536 +
                       (size_t)(n & 127) * 512 + (m & 511);
          obf[idx] = (__bf16)v;
        }
      }
    }
  }
}

// ---------------- adj: per-head column softmax, x1e4, CENTERED bf16, TRANSPOSED ----------------
__global__ __launch_bounds__(256) void adj_kernel(const float* __restrict__ ch_all,
                                                  const float* __restrict__ ct_all,
                                                  __bf16* __restrict__ adjT) {
  const int wave = threadIdx.x >> 6, lane = threadIdx.x & 63;
  const int row = blockIdx.x * 4 + wave;  // 0..4095
  const int h = row >> 9, i = row & 511;
  float ch[18];
  const float* chp = ch_all + ((size_t)h * 512 + i) * 18;
#pragma unroll
  for (int t = 0; t < 18; ++t) ch[t] = chp[t];
  float e[8];
  float m = -1e30f;
#pragma unroll
  for (int jj = 0; jj < 8; ++jj) {
    const int j = jj * 64 + lane;
    const float* ctp = ct_all + ((size_t)h * 512 + j) * 18;
    float d = 0.f;
#pragma unroll
    for (int t = 0; t < 18; ++t) d += ch[t] * ctp[t];
    if (j == i) d = 0.f;
    e[jj] = d;
    m = fmaxf(m, d);
  }
#pragma unroll
  for (int off = 32; off >= 1; off >>= 1) m = fmaxf(m, __shfl_xor(m, off));
  float s = 0.f;
#pragma unroll
  for (int jj = 0; jj < 8; ++jj) { e[jj] = __expf(e[jj] - m); s += e[jj]; }
#pragma unroll
  for (int off = 32; off >= 1; off >>= 1) s += __shfl_xor(s, off);
  const float inv = 10000.f / s;
  __bf16* op = adjT + (size_t)h * 262144 + i;  // column i of [512][512]
#pragma unroll
  for (int jj = 0; jj < 8; ++jj)
    op[(size_t)(jj * 64 + lane) * 512] = (__bf16)(e[jj] * inv - 19.53125f);
}

// ---------------- fused attention core: scores + row-softmax + PV ----------------
// NOW double-buffered with counted vmcnt (T3/T4): Bt0/Bt1 32KB, prologue stages
// ft0/ft1; steady state WAITV(8) (one tile's 8 loads stay in flight across
// barriers); fv0/fv1 staged during last QK phases so softmax covers their
// latency. LDS 80KB -> 2 blocks/CU (deliberate occupancy trade for overlap).
__global__ __launch_bounds__(256, 2) void fused_attn_kernel(
    const __bf16* __restrict__ fh, const __bf16* __restrict__ ft,
    const __bf16* __restrict__ fvT, const __bf16* __restrict__ adjT,
    float* __restrict__ fr, __bf16* __restrict__ ctx) {
  __shared__ alignas(16) __bf16 Bt0[128 * 128];   // 32 KB
  __shared__ alignas(16) __bf16 Bt1[128 * 128];   // 32 KB
  __shared__ alignas(16) __bf16 Pl[4][16 * 128];  // 16 KB, per-wave P chunk
  const int tid = threadIdx.x;
  const int l = tid & 63, w = tid >> 6;
  const int b = blockIdx.x;            // 0..31 -> XCD = b&7
  const int h = blockIdx.y >> 3;       // 0..7
  const int qt = blockIdx.y & 7;       // 0..7
  const int bh = b * 8 + h;
  const int wrow = qt * 64 + w * 16;
  const int lr = l & 15;
  const int khi = l >> 4;  // 0..3

  const int srow = tid >> 4;                 // row within 16-row group
  const int scc = (tid & 15) ^ (srow & 7);   // pre-swizzled source chunk

  // A fragments for QK^T (4 global 16B loads; retired by the first WAITV(8))
  bf8 afr[4];
  {
    const __bf16* ap = fh + (size_t)bh * 65536 + (size_t)(wrow + lr) * 128 + khi * 8;
#pragma unroll
    for (int kk4 = 0; kk4 < 4; ++kk4)
      afr[kk4] = *reinterpret_cast<const bf8*>(ap + kk4 * 32);
  }

  const __bf16* ftb = ft + (size_t)bh * 65536;
  const __bf16* fvb = fvT + (size_t)bh * 65536;

  auto stage_ft = [&](__bf16* dst, int kt) {
#pragma unroll
    for (int i = 0; i < 8; ++i)
      gload_lds16(ftb + (size_t)(kt * 128 + i * 16 + srow) * 128 + scc * 8,
                  dst + i * 2048 + tid * 8);
  };
  auto stage_fv = [&](__bf16* dst, int kt) {
#pragma unroll
    for (int i = 0; i < 8; ++i)
      gload_lds16(fvb + (size_t)(i * 16 + srow) * 512 + kt * 128 + scc * 8,
                  dst + i * 2048 + tid * 8);
  };

  f32x4 acc[32];
#pragma unroll
  for (int n = 0; n < 32; ++n)
#pragma unroll
    for (int e = 0; e < 4; ++e) acc[n][e] = 0.f;

  // ---- phase 1: S = fh . ft^T, 2-deep pipelined ----
  stage_ft(Bt0, 0);
  stage_ft(Bt1, 1);
#pragma unroll
  for (int kt = 0; kt < 4; ++kt) {
    __bf16* B = (kt & 1) ? Bt1 : Bt0;
    WAITV(8);   // kt0: retires afr(4)+ft0(8); ktN: retires ft(N), next tile stays in flight
    BARRIER();
    __builtin_amdgcn_s_setprio(1);
#pragma unroll
    for (int kk4 = 0; kk4 < 4; ++kk4) {
      bf8 bfr[8];
#pragma unroll
      for (int n2 = 0; n2 < 8; ++n2)
        bfr[n2] = *reinterpret_cast<const bf8*>(
            &B[(n2 * 16 + lr) * 128 + ((kk4 * 4 + khi) ^ (lr & 7)) * 8]);
#pragma unroll
      for (int n2 = 0; n2 < 8; ++n2)
        acc[kt * 8 + n2] =
            __builtin_amdgcn_mfma_f32_16x16x32_bf16(afr[kk4], bfr[n2], acc[kt * 8 + n2], 0, 0, 0);
    }
    __builtin_amdgcn_s_setprio(0);
    BARRIER();
    if (kt == 0) stage_ft(Bt0, 2);
    else if (kt == 1) stage_ft(Bt1, 3);
    else if (kt == 2) stage_fv(Bt0, 0);   // fv0 latency hidden under kt3 + softmax
    else stage_fv(Bt1, 1);                // fv1 hidden under softmax + fr write
  }

  // ---- phase 2: logits + in-register row softmax (fv0/fv1 in flight) ----
  const float scale = 0.08838834764831845f;  // 1/sqrt(128)
  const __bf16* adjTp = adjT + (size_t)h * 262144;
  float mrow[4] = {-1e30f, -1e30f, -1e30f, -1e30f};
#pragma unroll
  for (int n = 0; n < 32; ++n) {
    const int col = n * 16 + lr;
    bf4 av4 = *reinterpret_cast<const bf4*>(adjTp + (size_t)col * 512 + wrow + khi * 4);
#pragma unroll
    for (int r = 0; r < 4; ++r) {
      float v = acc[n][r] * scale + (float)av4[r];
      acc[n][r] = v;
      mrow[r] = fmaxf(mrow[r], v);
    }
  }
#pragma unroll
  for (int r = 0; r < 4; ++r)
#pragma unroll
    for (int off = 1; off <= 8; off <<= 1) mrow[r] = fmaxf(mrow[r], __shfl_xor(mrow[r], off));
  float srw[4] = {0.f, 0.f, 0.f, 0.f};
#pragma unroll
  for (int n = 0; n < 32; ++n)
#pragma unroll
    for (int r = 0; r < 4; ++r) {
      float e = __expf(acc[n][r] - mrow[r]);
      acc[n][r] = e;
      srw[r] += e;
    }
#pragma unroll
  for (int r = 0; r < 4; ++r)
#pragma unroll
    for (int off = 1; off <= 8; off <<= 1) srw[r] += __shfl_xor(srw[r], off);
  float inv[4];
#pragma unroll
  for (int r = 0; r < 4; ++r) inv[r] = 1.f / srw[r];
#pragma unroll
  for (int n = 0; n < 32; ++n)
#pragma unroll
    for (int r = 0; r < 4; ++r) acc[n][r] *= inv[r];

  // write fr (required output), once
  {
    float* frb = fr + (size_t)bh * 262144;
#pragma unroll
    for (int n = 0; n < 32; ++n) {
      const int col = n * 16 + lr;
#pragma unroll
      for (int r = 0; r < 4; ++r)
        frb[(size_t)(wrow + khi * 4 + r) * 512 + col] = acc[n][r];
    }
  }

  // ---- phase 3: PV, 2-deep pipelined ----
  f32x4 acc2[8];
#pragma unroll
  for (int n2 = 0; n2 < 8; ++n2)
#pragma unroll
    for (int e = 0; e < 4; ++e) acc2[n2][e] = 0.f;

  __bf16* Pw = &Pl[w][0];
#pragma unroll
  for (int kt = 0; kt < 4; ++kt) {
    __bf16* B = (kt & 1) ? Bt1 : Bt0;
    // bounce own P chunk kt into swizzled per-wave LDS (C-layout -> A-frag layout)
#pragma unroll
    for (int n2 = 0; n2 < 8; ++n2) {
      const int colc = n2 * 2 + (lr >> 3);
      const int cl = lr & 7;
#pragma unroll
      for (int r = 0; r < 4; ++r) {
        const int q = khi * 4 + r;
        Pw[q * 128 + ((colc ^ (q & 7)) * 8) + cl] = (__bf16)acc[kt * 8 + n2][r];
      }
    }
    LGKM0();             // own-wave P writes complete before pa reads
    if (kt < 3) { WAITV(8); } else { WAITV(0); }
    BARRIER();           // all waves' fv(kt) portions in LDS
    __builtin_amdgcn_s_setprio(1);
#pragma unroll
    for (int kk4 = 0; kk4 < 4; ++kk4) {
      bf8 pa = *reinterpret_cast<const bf8*>(
          &Pw[lr * 128 + ((kk4 * 4 + khi) ^ (lr & 7)) * 8]);
      bf8 bfr[8];
#pragma unroll
      for (int n2 = 0; n2 < 8; ++n2)
        bfr[n2] = *reinterpret_cast<const bf8*>(
            &B[(n2 * 16 + lr) * 128 + ((kk4 * 4 + khi) ^ (lr & 7)) * 8]);
#pragma unroll
      for (int n2 = 0; n2 < 8; ++n2)
        acc2[n2] = __builtin_amdgcn_mfma_f32_16x16x32_bf16(pa, bfr[n2], acc2[n2], 0, 0, 0);
    }
    __builtin_amdgcn_s_setprio(0);
    if (kt < 3) {
      BARRIER();
      if (kt == 0) stage_fv(Bt0, 2);
      else if (kt == 1) stage_fv(Bt1, 3);
    }
  }

#pragma unroll
  for (int n2 = 0; n2 < 8; ++n2) {
    const int c = n2 * 16 + lr;
#pragma unroll
    for (int r = 0; r < 4; ++r) {
      const int q = wrow + khi * 4 + r;
      ctx[(size_t)(b * 512 + q) * 1024 + h * 128 + c] = (__bf16)acc2[n2][r];
    }
  }
}

extern "C" void kernel_launch(void* const* d_in, const int* in_sizes, int n_in,
                              void* d_out, int out_size, void* d_ws, size_t ws_size,
                              hipStream_t stream) {
  const float* x_q  = (const float*)d_in[0];
  const float* x_kv = (const float*)d_in[1];
  const float* Wh   = (const float*)d_in[2];
  const float* bh   = (const float*)d_in[3];
  const float* Wv   = (const float*)d_in[4];
  const float* bv   = (const float*)d_in[5];
  const float* Wo   = (const float*)d_in[6];
  const float* bo   = (const float*)d_in[7];
  const float* rel  = (const float*)d_in[8];
  const float* colh = (const float*)d_in[9];
  const float* colt = (const float*)d_in[10];

  float* out = (float*)d_out;
  float* fr  = out + 16777216;  // 32*512*1024 floats, then 256*512*512 floats

  __bf16* xq_bf  = (__bf16*)d_ws;
  __bf16* xkv_bf = xq_bf + 16777216;
  __bf16* Wh_bf  = xkv_bf + 16777216;
  __bf16* Wv_bf  = Wh_bf + 1048576;
  __bf16* Wo_bf  = Wv_bf + 1048576;
  __bf16* fhead  = Wo_bf + 1048576;
  __bf16* ftail  = fhead + 16777216;
  __bf16* fvT    = ftail + 16777216;
  __bf16* adjT   = fvT + 16777216;
  __bf16* ctx    = adjT + 2097152;

  cvt_kernel<<<4096, 256, 0, stream>>>(x_q, xq_bf, 4194304);
  cvt_kernel<<<4096, 256, 0, stream>>>(x_kv, xkv_bf, 4194304);
  cvt_kernel<<<1024, 256, 0, stream>>>(Wh, Wh_bf, 262144);
  cvt_kernel<<<1024, 256, 0, stream>>>(Wv, Wv_bf, 262144);
  cvt_kernel<<<1024, 256, 0, stream>>>(Wo, Wo_bf, 262144);

  dim3 gp(64, 4);
  gemm_proj<0><<<gp, 512, 0, stream>>>(xq_bf, Wh_bf, bh, rel, fhead, nullptr);
  gemm_proj<0><<<gp, 512, 0, stream>>>(xkv_bf, Wh_bf, bh, rel, ftail, nullptr);
  gemm_proj<1><<<gp, 512, 0, stream>>>(xkv_bf, Wv_bf, bv, nullptr, fvT, nullptr);

  adj_kernel<<<1024, 256, 0, stream>>>(colh, colt, adjT);

  fused_attn_kernel<<<dim3(32, 64), 256, 0, stream>>>(fhead, ftail, fvT, adjT, fr, ctx);

  gemm_proj<2><<<gp, 512, 0, stream>>>(ctx, Wo_bf, bo, nullptr, nullptr, out);
}